// Round 7
// baseline (296.441 us; speedup 1.0000x reference)
//
#include <hip/hip_runtime.h>

// Problem: b=4, c=256, ci=128, h=w=64 (HW=4096), field=7, kk=49. fp32 I/O.
//
// 3-dispatch pipeline:
//  1. conv3: phi -> padded bf16 planes (ws), theta -> transposed bf16 (d_out),
//     g -> padded bf16 planes (ws). Plane borders zeroed in-kernel.
//  2. mega: per (b,j) block: scores (segmented flat-decode gather over padded
//     phi planes) -> LDS, softmax over h in LDS, aggregate over padded g
//     planes -> y bf16 (ws). attn never hits global memory.
//  3. maskconv: out = x + w_mask . y  (single full dispatch).
//
// Padded planes: [b][c0][70][72] bf16, data (py,px) at (py+3, px+4), zero
// borders. Patch value for flat index F -> (ch = F>>12, p = F&4095):
//   a = OFF(ch) + p + 8*(p>>6),  OFF(ch) = c0*5040 + kh*72 + kw + 1
// (c0 = ch/49, kh = (ch%49)/7, kw = ch%7). No bounds checks needed.
// Per-pixel F-range spans < 2*4096 so ch takes <=3 values -> 3 pure + 2
// mixed loop segments with wave-uniform OFF (verified in round 6).
//
// ws layout (ushort units):  A_phi @ 0 (2,580,480) | A_g @ 2,580,480
// (2,580,480) | y @ 5,160,960 (2,097,152)  => 14.5 MB total.
// d_out staging: theta bf16 [b][p][cc] @ 0 (4 MB), dead before maskconv.

#define PLANE    5040          // 70*72 ushort per c0 plane
#define A_BATCH  645120        // 128 * PLANE

__device__ __forceinline__ float bf2f(unsigned short u) {
    union { unsigned int i; float f; } v; v.i = ((unsigned int)u) << 16; return v.f;
}
__device__ __forceinline__ unsigned short f2bf(float f) {
    union { float f; unsigned int i; } v; v.f = f;
    unsigned int r = v.i + 0x7FFFu + ((v.i >> 16) & 1u);
    return (unsigned short)(r >> 16);
}

// ---------------------------------------------------------------------------
// conv3: fused phi/theta/g 1x1 convs. nt in [0,6): region = nt>>1
// (0=phi 1=theta 2=g), half = nt&1 selects rows [half*64, half*64+64).
// BM=64 x BN=64 x BK=16, 256 threads, 4x4 microtile, fp32 accumulate.
// phi/g: padded-plane bf16 store + distributed border zeroing.
// theta: transposed bf16 store [b][p][cc].
// ---------------------------------------------------------------------------
__global__ __launch_bounds__(256) void conv3_kernel(
    const float* __restrict__ x,
    const float* __restrict__ w_phi,
    const float* __restrict__ w_theta,
    const float* __restrict__ w_g,
    unsigned short* __restrict__ A_phi,
    unsigned short* __restrict__ theta_bf,
    unsigned short* __restrict__ A_g)
{
    const int tid = threadIdx.x;
    const int pt = blockIdx.x;    // pixel-row tile = py
    const int nt = blockIdx.y;    // 0..5
    const int b  = blockIdx.z;
    const int region = nt >> 1;
    const int nrow0 = (nt & 1) * 64;
    const float* __restrict__ W =
        (region == 0) ? w_phi : (region == 1) ? w_theta : w_g;

    __shared__ __align__(16) float sW[16 * 68];
    __shared__ __align__(16) float sX[16 * 68];

    const int tx = tid & 15;
    const int ty = tid >> 4;
    float acc[4][4] = {};

    // border zeroing for padded regions (disjoint from all data writes)
    if (region != 1) {
        unsigned short* __restrict__ Ar =
            ((region == 0) ? A_phi : A_g) + b * A_BATCH;
        // side borders of data row pt+3: cols 0..3, 68..71 for 64 planes
        #pragma unroll
        for (int e = tid; e < 512; e += 256) {
            int pl = e >> 3, c = e & 7;
            int col = (c < 4) ? c : (64 + c);
            Ar[(nrow0 + pl) * PLANE + (pt + 3) * 72 + col] = 0;
        }
        // top rows 0..2 and bottom rows 67..69 (blocks pt<3 handle one pair)
        if (pt < 3) {
            for (int e = tid; e < 64 * 72; e += 256) {
                int pl = e / 72, c = e - pl * 72;
                Ar[(nrow0 + pl) * PLANE + pt * 72 + c] = 0;
                Ar[(nrow0 + pl) * PLANE + (pt + 67) * 72 + c] = 0;
            }
        }
    }

    for (int kt = 0; kt < 16; ++kt) {
        #pragma unroll
        for (int e = 0; e < 4; ++e) {
            int lin = tid + e * 256;
            int kk = lin & 15, nn = lin >> 4;
            sW[kk * 68 + nn] = W[(nrow0 + nn) * 256 + kt * 16 + kk];
        }
        #pragma unroll
        for (int e = 0; e < 4; ++e) {
            int lin = tid + e * 256;
            int pp = lin & 63, kk = lin >> 6;
            sX[kk * 68 + pp] = x[(b * 256 + kt * 16 + kk) * 4096 + pt * 64 + pp];
        }
        __syncthreads();
        #pragma unroll
        for (int kk = 0; kk < 16; ++kk) {
            const float4 wv = *reinterpret_cast<const float4*>(&sW[kk * 68 + ty * 4]);
            const float4 xv = *reinterpret_cast<const float4*>(&sX[kk * 68 + tx * 4]);
            const float wr[4] = {wv.x, wv.y, wv.z, wv.w};
            const float xr[4] = {xv.x, xv.y, xv.z, xv.w};
            #pragma unroll
            for (int r = 0; r < 4; ++r)
                #pragma unroll
                for (int e = 0; e < 4; ++e)
                    acc[r][e] = fmaf(wr[r], xr[e], acc[r][e]);
        }
        __syncthreads();
    }

    if (region == 1) {
        // theta transposed: theta_bf[(b*4096 + p)*128 + cc]
        const int p0 = pt * 64 + tx * 4;
        const int cc0 = nrow0 + ty * 4;
        #pragma unroll
        for (int e = 0; e < 4; ++e) {
            ushort4 v;
            v.x = f2bf(acc[0][e]); v.y = f2bf(acc[1][e]);
            v.z = f2bf(acc[2][e]); v.w = f2bf(acc[3][e]);
            *reinterpret_cast<ushort4*>(&theta_bf[(b * 4096 + p0 + e) * 128 + cc0]) = v;
        }
    } else {
        unsigned short* __restrict__ A = (region == 0) ? A_phi : A_g;
        const unsigned wbase =
            (unsigned)(b * A_BATCH + (pt + 3) * 72 + tx * 4 + 4);
        #pragma unroll
        for (int r = 0; r < 4; ++r) {
            const int n = nrow0 + ty * 4 + r;
            ushort4 v;
            v.x = f2bf(acc[r][0]); v.y = f2bf(acc[r][1]);
            v.z = f2bf(acc[r][2]); v.w = f2bf(acc[r][3]);
            *reinterpret_cast<ushort4*>(&A[wbase + (unsigned)n * PLANE]) = v;
        }
    }
}

// ---------------------------------------------------------------------------
// mega: per (b, j) column block, 512 threads.
//  P1: stage theta (64 px x 128 cc) to LDS (fp32).
//  P2: scores for all i: wave w handles pixels i = w + 8*ii, lane = t.
//  P3: softmax over i (h axis) per column t, then scale tile by inv in LDS.
//  P4: aggregate: team (128 thr) handles pixels i = team + 4*ii, lane = cc;
//      y bf16 to ws.
// ---------------------------------------------------------------------------
__global__ __launch_bounds__(512) void mega_kernel(
    const unsigned short* __restrict__ A_phi,
    const unsigned short* __restrict__ theta_bf,
    const unsigned short* __restrict__ A_g,
    unsigned short* __restrict__ y_bf)
{
    const int j = blockIdx.x;
    const int b = blockIdx.y;
    const int tid = threadIdx.x;

    __shared__ float th[64][128];
    __shared__ float tile[64][52];
    __shared__ float inv[52];

    // P1: theta load (ushort4 vectorized: 2048 u4 / 512 thr = 4 each)
    #pragma unroll
    for (int it = 0; it < 4; ++it) {
        int e = tid + it * 512;
        int i = e >> 5;            // 32 ushort4 per pixel row
        int cq = (e & 31) << 2;    // cc base
        ushort4 v = *reinterpret_cast<const ushort4*>(
            &theta_bf[((b * 4096 + i * 64 + j) << 7) + cq]);
        th[i][cq]     = bf2f(v.x);
        th[i][cq + 1] = bf2f(v.y);
        th[i][cq + 2] = bf2f(v.z);
        th[i][cq + 3] = bf2f(v.w);
    }
    __syncthreads();

    const int w  = tid >> 6;
    const int ln = tid & 63;

    // P2: scores
    {
        const unsigned short* __restrict__ Ab = A_phi + b * A_BATCH;
        for (int ii = 0; ii < 8; ++ii) {
            const int i = w + (ii << 3);
            const int s = (i << 6) + j;

            const int base  = s * 6272;
            const int ch_lo = base >> 12;
            const unsigned B1 = (unsigned)(ch_lo + 1) << 12;
            const unsigned B2 = (unsigned)(ch_lo + 2) << 12;
            const int d1 = (int)B1 - base;        // in (0, 4096]
            const int d2 = d1 + 4096;

            int A1 = d1 / 49;
            int A2 = (d1 + 48) / 49;
            int C1 = d2 / 49;        if (C1 > 128) C1 = 128;
            int C2 = (d2 + 48) / 49; if (C2 > 128) C2 = 128;

            unsigned OFFv[3];
            #pragma unroll
            for (int q = 0; q < 3; ++q) {
                int ch = ch_lo + q;
                int c0 = ch / 49; if (c0 > 127) c0 = 127;
                int rr = ch - c0 * 49;
                int kh = rr / 7;
                int kw = rr - kh * 7;
                OFFv[q] = (unsigned)(c0 * PLANE + kh * 72 + kw + 1);
            }

            unsigned F = (unsigned)(base + ln);
            float acc = 0.f;
            {
                const unsigned OFF_ = OFFv[0];
                #pragma unroll 4
                for (int cc = 0; cc < A1; ++cc) {
                    unsigned p = F & 4095u;
                    unsigned a = OFF_ + p + ((p >> 6) << 3);
                    acc = fmaf(th[i][cc], bf2f(Ab[a]), acc);
                    F += 49u;
                }
            }
            for (int cc = A1; cc < A2; ++cc) {
                unsigned OFF_ = (F >= B1) ? OFFv[1] : OFFv[0];
                unsigned p = F & 4095u;
                unsigned a = OFF_ + p + ((p >> 6) << 3);
                acc = fmaf(th[i][cc], bf2f(Ab[a]), acc);
                F += 49u;
            }
            {
                const unsigned OFF_ = OFFv[1];
                #pragma unroll 4
                for (int cc = A2; cc < C1; ++cc) {
                    unsigned p = F & 4095u;
                    unsigned a = OFF_ + p + ((p >> 6) << 3);
                    acc = fmaf(th[i][cc], bf2f(Ab[a]), acc);
                    F += 49u;
                }
            }
            for (int cc = C1; cc < C2; ++cc) {
                unsigned OFF_ = (F >= B2) ? OFFv[2] : OFFv[1];
                unsigned p = F & 4095u;
                unsigned a = OFF_ + p + ((p >> 6) << 3);
                acc = fmaf(th[i][cc], bf2f(Ab[a]), acc);
                F += 49u;
            }
            {
                const unsigned OFF_ = OFFv[2];
                #pragma unroll 4
                for (int cc = C2; cc < 128; ++cc) {
                    unsigned p = F & 4095u;
                    unsigned a = OFF_ + p + ((p >> 6) << 3);
                    acc = fmaf(th[i][cc], bf2f(Ab[a]), acc);
                    F += 49u;
                }
            }
            if (ln < 49) tile[i][ln] = acc;
        }
    }
    __syncthreads();

    // P3: softmax over i for each column t, then scale rows by inv
    if (tid < 49) {
        float m = -3.4e38f;
        #pragma unroll 8
        for (int i = 0; i < 64; ++i) m = fmaxf(m, tile[i][tid]);
        float sum = 0.f;
        #pragma unroll 8
        for (int i = 0; i < 64; ++i) {
            float e = __expf(tile[i][tid] - m);
            tile[i][tid] = e;
            sum += e;
        }
        inv[tid] = 1.f / sum;
    }
    __syncthreads();
    #pragma unroll
    for (int ii = 0; ii < 8; ++ii) {
        int i = w + (ii << 3);
        if (ln < 49) tile[i][ln] *= inv[ln];
    }
    __syncthreads();

    // P4: aggregate -> y
    {
        const int team = tid >> 7;        // 0..3
        const int cc   = tid & 127;
        const unsigned short* __restrict__ Gb = A_g + b * A_BATCH;
        for (int ii = 0; ii < 16; ++ii) {
            const int i = team + (ii << 2);
            const int s = (i << 6) + j;

            const int base  = s * 6272;
            const int ch_lo = base >> 12;
            const unsigned B1 = (unsigned)(ch_lo + 1) << 12;
            const unsigned B2 = (unsigned)(ch_lo + 2) << 12;
            const int d1 = (int)B1 - base;
            const int d2 = d1 + 4096;

            int A1 = d1 >> 7;
            int A2 = (d1 + 127) >> 7;
            int C1 = d2 >> 7;          if (C1 > 49) C1 = 49;
            int C2 = (d2 + 127) >> 7;  if (C2 > 49) C2 = 49;
            if (A1 > 49) A1 = 49;
            if (A2 > 49) A2 = 49;

            unsigned OFFv[3];
            #pragma unroll
            for (int q = 0; q < 3; ++q) {
                int ch = ch_lo + q;
                int c0 = ch / 49; if (c0 > 127) c0 = 127;
                int rr = ch - c0 * 49;
                int kh = rr / 7;
                int kw = rr - kh * 7;
                OFFv[q] = (unsigned)(c0 * PLANE + kh * 72 + kw + 1);
            }

            unsigned F = (unsigned)(base + cc);
            float acc = 0.f;
            {
                const unsigned OFF_ = OFFv[0];
                #pragma unroll 4
                for (int t = 0; t < A1; ++t) {
                    unsigned p = F & 4095u;
                    unsigned a = OFF_ + p + ((p >> 6) << 3);
                    acc = fmaf(tile[i][t], bf2f(Gb[a]), acc);
                    F += 128u;
                }
            }
            for (int t = A1; t < A2; ++t) {
                unsigned OFF_ = (F >= B1) ? OFFv[1] : OFFv[0];
                unsigned p = F & 4095u;
                unsigned a = OFF_ + p + ((p >> 6) << 3);
                acc = fmaf(tile[i][t], bf2f(Gb[a]), acc);
                F += 128u;
            }
            {
                const unsigned OFF_ = OFFv[1];
                #pragma unroll 4
                for (int t = A2; t < C1; ++t) {
                    unsigned p = F & 4095u;
                    unsigned a = OFF_ + p + ((p >> 6) << 3);
                    acc = fmaf(tile[i][t], bf2f(Gb[a]), acc);
                    F += 128u;
                }
            }
            for (int t = C1; t < C2; ++t) {
                unsigned OFF_ = (F >= B2) ? OFFv[2] : OFFv[1];
                unsigned p = F & 4095u;
                unsigned a = OFF_ + p + ((p >> 6) << 3);
                acc = fmaf(tile[i][t], bf2f(Gb[a]), acc);
                F += 128u;
            }
            {
                const unsigned OFF_ = OFFv[2];
                for (int t = C2; t < 49; ++t) {
                    unsigned p = F & 4095u;
                    unsigned a = OFF_ + p + ((p >> 6) << 3);
                    acc = fmaf(tile[i][t], bf2f(Gb[a]), acc);
                    F += 128u;
                }
            }
            y_bf[(b * 4096 + s) * 128 + cc] = f2bf(acc);
        }
    }
}

// ---------------------------------------------------------------------------
// maskconv: out[b,o,p] = x[b,o,p] + sum_cc w_mask[o,cc] * y[b,p,cc]
// BM=64 x BN=64 x BK=16, K=128; full batch in one dispatch.
// ---------------------------------------------------------------------------
__global__ __launch_bounds__(256) void maskconv_kernel(
    const float* __restrict__ x,
    const float* __restrict__ w_mask,
    const unsigned short* __restrict__ y_bf,
    float* __restrict__ out)
{
    const int tid = threadIdx.x;
    const int pt = blockIdx.x;
    const int ot = blockIdx.y;
    const int b  = blockIdx.z;

    __shared__ __align__(16) float sW[16 * 68];
    __shared__ __align__(16) float sX[16 * 68];

    const int tx = tid & 15;
    const int ty = tid >> 4;
    float acc[4][4] = {};

    for (int kt = 0; kt < 8; ++kt) {
        #pragma unroll
        for (int e = 0; e < 4; ++e) {
            int lin = tid + e * 256;
            int kk = lin & 15, nn = lin >> 4;
            sW[kk * 68 + nn] = w_mask[(ot * 64 + nn) * 128 + kt * 16 + kk];
        }
        #pragma unroll
        for (int e = 0; e < 4; ++e) {
            int lin = tid + e * 256;
            int kk = lin & 15, pp = lin >> 4;
            sX[kk * 68 + pp] =
                bf2f(y_bf[(b * 4096 + pt * 64 + pp) * 128 + kt * 16 + kk]);
        }
        __syncthreads();
        #pragma unroll
        for (int kk = 0; kk < 16; ++kk) {
            const float4 wv = *reinterpret_cast<const float4*>(&sW[kk * 68 + ty * 4]);
            const float4 xv = *reinterpret_cast<const float4*>(&sX[kk * 68 + tx * 4]);
            const float wr[4] = {wv.x, wv.y, wv.z, wv.w};
            const float xr[4] = {xv.x, xv.y, xv.z, xv.w};
            #pragma unroll
            for (int r = 0; r < 4; ++r)
                #pragma unroll
                for (int e = 0; e < 4; ++e)
                    acc[r][e] = fmaf(wr[r], xr[e], acc[r][e]);
        }
        __syncthreads();
    }

    const int p0 = pt * 64 + tx * 4;
    #pragma unroll
    for (int r = 0; r < 4; ++r) {
        const int o = ot * 64 + ty * 4 + r;
        const int ofs = (b * 256 + o) * 4096 + p0;
        const float4 xr4 = *reinterpret_cast<const float4*>(&x[ofs]);
        float4 v = make_float4(acc[r][0] + xr4.x, acc[r][1] + xr4.y,
                               acc[r][2] + xr4.z, acc[r][3] + xr4.w);
        *reinterpret_cast<float4*>(&out[ofs]) = v;
    }
}

extern "C" void kernel_launch(void* const* d_in, const int* in_sizes, int n_in,
                              void* d_out, int out_size, void* d_ws, size_t ws_size,
                              hipStream_t stream) {
    const float* x       = (const float*)d_in[0];
    const float* w_phi   = (const float*)d_in[1];
    const float* w_theta = (const float*)d_in[2];
    const float* w_g     = (const float*)d_in[3];
    const float* w_mask  = (const float*)d_in[4];

    float* out_f = (float*)d_out;

    unsigned short* ws_u   = (unsigned short*)d_ws;
    unsigned short* A_phi  = ws_u;                    // 2,580,480 ush
    unsigned short* A_g    = ws_u + 2580480;          // 2,580,480 ush
    unsigned short* y_u    = ws_u + 5160960;          // 2,097,152 ush
    unsigned short* th_out = (unsigned short*)d_out;  // theta staged in d_out

    // 1: phi/theta/g fused
    hipLaunchKernelGGL(conv3_kernel, dim3(64, 6, 4), dim3(256), 0, stream,
                       x, w_phi, w_theta, w_g, A_phi, th_out, A_g);
    // 2: scores + softmax + aggregate
    hipLaunchKernelGGL(mega_kernel, dim3(64, 4), dim3(512), 0, stream,
                       A_phi, th_out, A_g, y_u);
    // 3: maskconv + residual -> out
    hipLaunchKernelGGL(maskconv_kernel, dim3(64, 4, 4), dim3(256), 0, stream,
                       x, w_mask, y_u, out_f);
}

// Round 8
// 229.573 us; speedup vs baseline: 1.2913x; 1.2913x over previous
//
#include <hip/hip_runtime.h>

// Problem: b=4, c=256, ci=128, h=w=64 (HW=4096), field=7, kk=49. fp32 I/O.
//
// 5-dispatch pipeline (ws is large — ~256 MB — per round-6 poison evidence):
//  1. conv3: phi -> padded bf16 planes, theta -> transposed bf16, g -> padded
//     planes. Borders zeroed in-kernel. (1536 blocks)
//  2. scores: segmented flat-decode gather, wave per pixel. (4096 blocks)
//  3. softmax over h per (b,j). (256 blocks)
//  4. aggregate: segmented gather, 2 px/block. (8192 blocks)
//  5. maskconv + residual. (1024 blocks)
//
// Padded planes: [b][c0][70][72] bf16, data (py,px) at (py+3, px+4), zero
// borders. Patch value for flat index F -> (ch = F>>12, p = F&4095):
//   a = OFF(ch) + p + 8*(p>>6),  OFF(ch) = c0*5040 + kh*72 + kw + 1
// (c0 = ch/49, kh = (ch%49)/7, kw = ch%7). No bounds checks. Per-pixel
// F-range spans < 2*4096 so ch takes <=3 values -> 3 pure + 2 mixed
// segments with wave-uniform OFF (verified rounds 6-7).
//
// ws layout (ushort units):
//   A_phi @ 0          (2,580,480)
//   A_g   @ 2,580,480  (2,580,480)
//   y     @ 5,160,960  (2,097,152)
//   theta @ 7,258,112  (2,097,152)
//   scores(fp32) @ float index 4,677,632  (1,048,576 floats)  => ~22.7 MB

#define PLANE    5040
#define A_BATCH  645120

__device__ __forceinline__ float bf2f(unsigned short u) {
    union { unsigned int i; float f; } v; v.i = ((unsigned int)u) << 16; return v.f;
}
__device__ __forceinline__ unsigned short f2bf(float f) {
    union { float f; unsigned int i; } v; v.f = f;
    unsigned int r = v.i + 0x7FFFu + ((v.i >> 16) & 1u);
    return (unsigned short)(r >> 16);
}

// ---------------------------------------------------------------------------
// conv3: fused phi/theta/g 1x1 convs. nt in [0,6): region = nt>>1
// (0=phi 1=theta 2=g), rows [ (nt&1)*64, +64 ). BM=64 x BN=64 x BK=16.
// ---------------------------------------------------------------------------
__global__ __launch_bounds__(256) void conv3_kernel(
    const float* __restrict__ x,
    const float* __restrict__ w_phi,
    const float* __restrict__ w_theta,
    const float* __restrict__ w_g,
    unsigned short* __restrict__ A_phi,
    unsigned short* __restrict__ theta_bf,
    unsigned short* __restrict__ A_g)
{
    const int tid = threadIdx.x;
    const int pt = blockIdx.x;    // pixel-row tile = py
    const int nt = blockIdx.y;    // 0..5
    const int b  = blockIdx.z;
    const int region = nt >> 1;
    const int nrow0 = (nt & 1) * 64;
    const float* __restrict__ W =
        (region == 0) ? w_phi : (region == 1) ? w_theta : w_g;

    __shared__ __align__(16) float sW[16 * 68];
    __shared__ __align__(16) float sX[16 * 68];

    const int tx = tid & 15;
    const int ty = tid >> 4;
    float acc[4][4] = {};

    // border zeroing for padded regions (disjoint from all data writes)
    if (region != 1) {
        unsigned short* __restrict__ Ar =
            ((region == 0) ? A_phi : A_g) + b * A_BATCH;
        #pragma unroll
        for (int e = tid; e < 512; e += 256) {
            int pl = e >> 3, c = e & 7;
            int col = (c < 4) ? c : (64 + c);
            Ar[(nrow0 + pl) * PLANE + (pt + 3) * 72 + col] = 0;
        }
        if (pt < 3) {
            for (int e = tid; e < 64 * 72; e += 256) {
                int pl = e / 72, c = e - pl * 72;
                Ar[(nrow0 + pl) * PLANE + pt * 72 + c] = 0;
                Ar[(nrow0 + pl) * PLANE + (pt + 67) * 72 + c] = 0;
            }
        }
    }

    for (int kt = 0; kt < 16; ++kt) {
        #pragma unroll
        for (int e = 0; e < 4; ++e) {
            int lin = tid + e * 256;
            int kk = lin & 15, nn = lin >> 4;
            sW[kk * 68 + nn] = W[(nrow0 + nn) * 256 + kt * 16 + kk];
        }
        #pragma unroll
        for (int e = 0; e < 4; ++e) {
            int lin = tid + e * 256;
            int pp = lin & 63, kk = lin >> 6;
            sX[kk * 68 + pp] = x[(b * 256 + kt * 16 + kk) * 4096 + pt * 64 + pp];
        }
        __syncthreads();
        #pragma unroll
        for (int kk = 0; kk < 16; ++kk) {
            const float4 wv = *reinterpret_cast<const float4*>(&sW[kk * 68 + ty * 4]);
            const float4 xv = *reinterpret_cast<const float4*>(&sX[kk * 68 + tx * 4]);
            const float wr[4] = {wv.x, wv.y, wv.z, wv.w};
            const float xr[4] = {xv.x, xv.y, xv.z, xv.w};
            #pragma unroll
            for (int r = 0; r < 4; ++r)
                #pragma unroll
                for (int e = 0; e < 4; ++e)
                    acc[r][e] = fmaf(wr[r], xr[e], acc[r][e]);
        }
        __syncthreads();
    }

    if (region == 1) {
        const int p0 = pt * 64 + tx * 4;
        const int cc0 = nrow0 + ty * 4;
        #pragma unroll
        for (int e = 0; e < 4; ++e) {
            ushort4 v;
            v.x = f2bf(acc[0][e]); v.y = f2bf(acc[1][e]);
            v.z = f2bf(acc[2][e]); v.w = f2bf(acc[3][e]);
            *reinterpret_cast<ushort4*>(&theta_bf[(b * 4096 + p0 + e) * 128 + cc0]) = v;
        }
    } else {
        unsigned short* __restrict__ A = (region == 0) ? A_phi : A_g;
        const unsigned wbase =
            (unsigned)(b * A_BATCH + (pt + 3) * 72 + tx * 4 + 4);
        #pragma unroll
        for (int r = 0; r < 4; ++r) {
            const int n = nrow0 + ty * 4 + r;
            ushort4 v;
            v.x = f2bf(acc[r][0]); v.y = f2bf(acc[r][1]);
            v.z = f2bf(acc[r][2]); v.w = f2bf(acc[r][3]);
            *reinterpret_cast<ushort4*>(&A[wbase + (unsigned)n * PLANE]) = v;
        }
    }
}

// ---------------------------------------------------------------------------
// scores: wave per pixel s, lane = t. 3 pure + 2 mixed cc-segments over
// padded phi planes. scores fp32 slots [b][s][64] (first 49 used).
// ---------------------------------------------------------------------------
__global__ __launch_bounds__(256) void scores_kernel(
    const unsigned short* __restrict__ Apad,
    const unsigned short* __restrict__ theta_bf,
    float* __restrict__ scores)
{
    const int w  = threadIdx.x >> 6;
    const int ln = threadIdx.x & 63;
    const int s  = blockIdx.x * 4 + w;
    const int b  = blockIdx.y;

    __shared__ float th[4][128];
    {
        const unsigned short* tb = theta_bf + (b * 4096 + s) * 128;
        th[w][ln]      = bf2f(tb[ln]);
        th[w][ln + 64] = bf2f(tb[ln + 64]);
    }
    __syncthreads();

    const unsigned short* __restrict__ Ab = Apad + b * A_BATCH;

    const int base  = s * 6272;
    const int ch_lo = base >> 12;
    const unsigned B1 = (unsigned)(ch_lo + 1) << 12;
    const unsigned B2 = (unsigned)(ch_lo + 2) << 12;
    const int d1 = (int)B1 - base;
    const int d2 = d1 + 4096;

    int A1 = d1 / 49;
    int A2 = (d1 + 48) / 49;
    int C1 = d2 / 49;        if (C1 > 128) C1 = 128;
    int C2 = (d2 + 48) / 49; if (C2 > 128) C2 = 128;

    unsigned OFFv[3];
    #pragma unroll
    for (int i = 0; i < 3; ++i) {
        int ch = ch_lo + i;
        int c0 = ch / 49; if (c0 > 127) c0 = 127;
        int rr = ch - c0 * 49;
        int kh = rr / 7;
        int kw = rr - kh * 7;
        OFFv[i] = (unsigned)(c0 * PLANE + kh * 72 + kw + 1);
    }

    unsigned F = (unsigned)(base + ln);
    float acc = 0.f;

    {
        const unsigned OFF_ = OFFv[0];
        #pragma unroll 4
        for (int cc = 0; cc < A1; ++cc) {
            unsigned p = F & 4095u;
            unsigned a = OFF_ + p + ((p >> 6) << 3);
            acc = fmaf(th[w][cc], bf2f(Ab[a]), acc);
            F += 49u;
        }
    }
    for (int cc = A1; cc < A2; ++cc) {
        unsigned OFF_ = (F >= B1) ? OFFv[1] : OFFv[0];
        unsigned p = F & 4095u;
        unsigned a = OFF_ + p + ((p >> 6) << 3);
        acc = fmaf(th[w][cc], bf2f(Ab[a]), acc);
        F += 49u;
    }
    {
        const unsigned OFF_ = OFFv[1];
        #pragma unroll 4
        for (int cc = A2; cc < C1; ++cc) {
            unsigned p = F & 4095u;
            unsigned a = OFF_ + p + ((p >> 6) << 3);
            acc = fmaf(th[w][cc], bf2f(Ab[a]), acc);
            F += 49u;
        }
    }
    for (int cc = C1; cc < C2; ++cc) {
        unsigned OFF_ = (F >= B2) ? OFFv[2] : OFFv[1];
        unsigned p = F & 4095u;
        unsigned a = OFF_ + p + ((p >> 6) << 3);
        acc = fmaf(th[w][cc], bf2f(Ab[a]), acc);
        F += 49u;
    }
    {
        const unsigned OFF_ = OFFv[2];
        #pragma unroll 4
        for (int cc = C2; cc < 128; ++cc) {
            unsigned p = F & 4095u;
            unsigned a = OFF_ + p + ((p >> 6) << 3);
            acc = fmaf(th[w][cc], bf2f(Ab[a]), acc);
            F += 49u;
        }
    }

    if (ln < 49) scores[(b * 4096 + s) * 64 + ln] = acc;
}

// ---------------------------------------------------------------------------
// softmax over h (axis=1): block per (b,j); LDS-transpose 64(i) x 49(t).
// ---------------------------------------------------------------------------
__global__ __launch_bounds__(256) void softmax_kernel(float* __restrict__ scores)
{
    const int b = blockIdx.x >> 6;
    const int j = blockIdx.x & 63;
    const int tid = threadIdx.x;
    const int wv = tid >> 6;
    const int ln = tid & 63;

    __shared__ float tile[64][52];
    __shared__ float inv[52];

    #pragma unroll
    for (int it = 0; it < 16; ++it) {
        int i = it * 4 + wv;
        if (ln < 49) tile[i][ln] = scores[(b * 4096 + i * 64 + j) * 64 + ln];
    }
    __syncthreads();

    if (tid < 49) {
        float m = -3.4e38f;
        #pragma unroll 8
        for (int i = 0; i < 64; ++i) m = fmaxf(m, tile[i][tid]);
        float sum = 0.f;
        #pragma unroll 8
        for (int i = 0; i < 64; ++i) {
            float e = __expf(tile[i][tid] - m);
            tile[i][tid] = e;
            sum += e;
        }
        inv[tid] = 1.f / sum;
    }
    __syncthreads();

    #pragma unroll
    for (int it = 0; it < 16; ++it) {
        int i = it * 4 + wv;
        if (ln < 49) scores[(b * 4096 + i * 64 + j) * 64 + ln] = tile[i][ln] * inv[ln];
    }
}

// ---------------------------------------------------------------------------
// aggregate: 2 pixels/block, lane = cc (128). Segment trick over t.
// y bf16 [b][s][cc] to ws.
// ---------------------------------------------------------------------------
__global__ __launch_bounds__(256) void aggregate_kernel(
    const float* __restrict__ scores,
    const unsigned short* __restrict__ Apad,
    unsigned short* __restrict__ y_bf)
{
    const int pix = threadIdx.x >> 7;
    const int cc  = threadIdx.x & 127;
    const int s   = blockIdx.x * 2 + pix;
    const int b   = blockIdx.y;

    __shared__ float at[2][52];
    if (cc < 49) at[pix][cc] = scores[(b * 4096 + s) * 64 + cc];
    __syncthreads();

    const unsigned short* __restrict__ Ab = Apad + b * A_BATCH;

    const int base  = s * 6272;
    const int ch_lo = base >> 12;
    const unsigned B1 = (unsigned)(ch_lo + 1) << 12;
    const unsigned B2 = (unsigned)(ch_lo + 2) << 12;
    const int d1 = (int)B1 - base;
    const int d2 = d1 + 4096;

    int A1 = d1 >> 7;
    int A2 = (d1 + 127) >> 7;
    int C1 = d2 >> 7;          if (C1 > 49) C1 = 49;
    int C2 = (d2 + 127) >> 7;  if (C2 > 49) C2 = 49;
    if (A1 > 49) A1 = 49;
    if (A2 > 49) A2 = 49;

    unsigned OFFv[3];
    #pragma unroll
    for (int i = 0; i < 3; ++i) {
        int ch = ch_lo + i;
        int c0 = ch / 49; if (c0 > 127) c0 = 127;
        int rr = ch - c0 * 49;
        int kh = rr / 7;
        int kw = rr - kh * 7;
        OFFv[i] = (unsigned)(c0 * PLANE + kh * 72 + kw + 1);
    }

    unsigned F = (unsigned)(base + cc);
    float acc = 0.f;

    {
        const unsigned OFF_ = OFFv[0];
        #pragma unroll 4
        for (int t = 0; t < A1; ++t) {
            unsigned p = F & 4095u;
            unsigned a = OFF_ + p + ((p >> 6) << 3);
            acc = fmaf(at[pix][t], bf2f(Ab[a]), acc);
            F += 128u;
        }
    }
    for (int t = A1; t < A2; ++t) {
        unsigned OFF_ = (F >= B1) ? OFFv[1] : OFFv[0];
        unsigned p = F & 4095u;
        unsigned a = OFF_ + p + ((p >> 6) << 3);
        acc = fmaf(at[pix][t], bf2f(Ab[a]), acc);
        F += 128u;
    }
    {
        const unsigned OFF_ = OFFv[1];
        #pragma unroll 4
        for (int t = A2; t < C1; ++t) {
            unsigned p = F & 4095u;
            unsigned a = OFF_ + p + ((p >> 6) << 3);
            acc = fmaf(at[pix][t], bf2f(Ab[a]), acc);
            F += 128u;
        }
    }
    for (int t = C1; t < C2; ++t) {
        unsigned OFF_ = (F >= B2) ? OFFv[2] : OFFv[1];
        unsigned p = F & 4095u;
        unsigned a = OFF_ + p + ((p >> 6) << 3);
        acc = fmaf(at[pix][t], bf2f(Ab[a]), acc);
        F += 128u;
    }
    {
        const unsigned OFF_ = OFFv[2];
        for (int t = C2; t < 49; ++t) {
            unsigned p = F & 4095u;
            unsigned a = OFF_ + p + ((p >> 6) << 3);
            acc = fmaf(at[pix][t], bf2f(Ab[a]), acc);
            F += 128u;
        }
    }

    y_bf[(b * 4096 + s) * 128 + cc] = f2bf(acc);
}

// ---------------------------------------------------------------------------
// maskconv: out[b,o,p] = x[b,o,p] + sum_cc w_mask[o,cc] * y[b,p,cc]
// BM=64 x BN=64 x BK=16, K=128; full batch in one dispatch.
// ---------------------------------------------------------------------------
__global__ __launch_bounds__(256) void maskconv_kernel(
    const float* __restrict__ x,
    const float* __restrict__ w_mask,
    const unsigned short* __restrict__ y_bf,
    float* __restrict__ out)
{
    const int tid = threadIdx.x;
    const int pt = blockIdx.x;
    const int ot = blockIdx.y;
    const int b  = blockIdx.z;

    __shared__ __align__(16) float sW[16 * 68];
    __shared__ __align__(16) float sX[16 * 68];

    const int tx = tid & 15;
    const int ty = tid >> 4;
    float acc[4][4] = {};

    for (int kt = 0; kt < 8; ++kt) {
        #pragma unroll
        for (int e = 0; e < 4; ++e) {
            int lin = tid + e * 256;
            int kk = lin & 15, nn = lin >> 4;
            sW[kk * 68 + nn] = w_mask[(ot * 64 + nn) * 128 + kt * 16 + kk];
        }
        #pragma unroll
        for (int e = 0; e < 4; ++e) {
            int lin = tid + e * 256;
            int kk = lin & 15, pp = lin >> 4;
            sX[kk * 68 + pp] =
                bf2f(y_bf[(b * 4096 + pt * 64 + pp) * 128 + kt * 16 + kk]);
        }
        __syncthreads();
        #pragma unroll
        for (int kk = 0; kk < 16; ++kk) {
            const float4 wv = *reinterpret_cast<const float4*>(&sW[kk * 68 + ty * 4]);
            const float4 xv = *reinterpret_cast<const float4*>(&sX[kk * 68 + tx * 4]);
            const float wr[4] = {wv.x, wv.y, wv.z, wv.w};
            const float xr[4] = {xv.x, xv.y, xv.z, xv.w};
            #pragma unroll
            for (int r = 0; r < 4; ++r)
                #pragma unroll
                for (int e = 0; e < 4; ++e)
                    acc[r][e] = fmaf(wr[r], xr[e], acc[r][e]);
        }
        __syncthreads();
    }

    const int p0 = pt * 64 + tx * 4;
    #pragma unroll
    for (int r = 0; r < 4; ++r) {
        const int o = ot * 64 + ty * 4 + r;
        const int ofs = (b * 256 + o) * 4096 + p0;
        const float4 xr4 = *reinterpret_cast<const float4*>(&x[ofs]);
        float4 v = make_float4(acc[r][0] + xr4.x, acc[r][1] + xr4.y,
                               acc[r][2] + xr4.z, acc[r][3] + xr4.w);
        *reinterpret_cast<float4*>(&out[ofs]) = v;
    }
}

extern "C" void kernel_launch(void* const* d_in, const int* in_sizes, int n_in,
                              void* d_out, int out_size, void* d_ws, size_t ws_size,
                              hipStream_t stream) {
    const float* x       = (const float*)d_in[0];
    const float* w_phi   = (const float*)d_in[1];
    const float* w_theta = (const float*)d_in[2];
    const float* w_g     = (const float*)d_in[3];
    const float* w_mask  = (const float*)d_in[4];

    float* out_f = (float*)d_out;

    unsigned short* ws_u  = (unsigned short*)d_ws;
    unsigned short* A_phi = ws_u;                     // 2,580,480 ush
    unsigned short* A_g   = ws_u + 2580480;           // 2,580,480 ush
    unsigned short* y_u   = ws_u + 5160960;           // 2,097,152 ush
    unsigned short* th_u  = ws_u + 7258112;           // 2,097,152 ush
    float*          sc_f  = (float*)d_ws + 4677632;   // 1,048,576 fp32

    // 1: phi/theta/g fused
    hipLaunchKernelGGL(conv3_kernel, dim3(64, 6, 4), dim3(256), 0, stream,
                       x, w_phi, w_theta, w_g, A_phi, th_u, A_g);
    // 2: scores
    hipLaunchKernelGGL(scores_kernel, dim3(1024, 4), dim3(256), 0, stream,
                       A_phi, th_u, sc_f);
    // 3: softmax over h
    hipLaunchKernelGGL(softmax_kernel, dim3(256), dim3(256), 0, stream, sc_f);
    // 4: aggregate -> y bf16
    hipLaunchKernelGGL(aggregate_kernel, dim3(2048, 4), dim3(256), 0, stream,
                       sc_f, A_phi == A_g ? A_g : A_g, y_u);
    // 5: maskconv + residual -> out
    hipLaunchKernelGGL(maskconv_kernel, dim3(64, 4, 4), dim3(256), 0, stream,
                       x, w_mask, y_u, out_f);
}

// Round 10
// 225.678 us; speedup vs baseline: 1.3136x; 1.0173x over previous
//
#include <hip/hip_runtime.h>

// Problem: b=4, c=256, ci=128, h=w=64 (HW=4096), field=7, kk=49. fp32 I/O.
//
// 6-dispatch pipeline, MFMA GEMMs with split-bf16 (hi+lo) operands to keep
// round-8 fp32-grade conv numerics (absmax 0.117):
//  1. prep: x -> x_hi/x_lo bf16 [b][p][k] (LDS transpose + residual split),
//     w3_hi/lo + wm_hi/lo casts, zero padded-plane regions.
//  2. conv3_mfma: acc += Ahi.Bhi + Ahi.Blo + Alo.Bhi (3 MFMAs/pair);
//     epilogue: phi->planes, theta->[p][cc], g->planes (bf16).
//  3. scores: segmented flat-decode gather (verified r6-8).
//  4. softmax over h per (b,j) (verified).
//  5. aggregate: segmented gather (verified).
//  6. maskconv_mfma: (wm_hi + wm_lo).y + x -> out (2 MFMAs/pair, fp32 out).
//
// Padded planes: [b][c0][70][72] bf16, data (py,px) at (py+3, px+4), zero
// borders. Patch value for flat index F -> (ch=F>>12, p=F&4095):
//   a = OFF(ch) + p + 8*(p>>6), OFF(ch) = c0*5040 + kh*72 + kw + 1.
// Per-pixel F-range < 2*4096 -> ch takes <=3 values -> 3 pure + 2 mixed
// segments with wave-uniform OFF (verified rounds 6-8).
//
// MFMA layouts (r9-verified): A[m=lane&15][k=quad*8+j],
// B[k=quad*8+j][n=lane&15], C/D col=lane&15, row=quad*4+reg.
//
// ws layout (ushort units):
//   A_phi  @ 0          (2,580,480)
//   A_g    @ 2,580,480  (2,580,480)   (zeroed contiguously with A_phi)
//   y      @ 5,160,960  (2,097,152)
//   theta  @ 7,258,112  (2,097,152)
//   scores @ 9,355,264  (2,097,152 ush = 1,048,576 fp32)
//   x_hi   @ 11,452,416 (4,194,304)
//   x_lo   @ 15,646,720 (4,194,304)
//   w3_hi  @ 19,841,024 (98,304)
//   w3_lo  @ 19,939,328 (98,304)
//   wm_hi  @ 20,037,632 (32,768)
//   wm_lo  @ 20,070,400 (32,768)     => ~40.2 MB total

#define PLANE    5040
#define A_BATCH  645120

typedef __attribute__((ext_vector_type(8))) short short8;
typedef __attribute__((ext_vector_type(4))) float floatx4;

__device__ __forceinline__ float bf2f(unsigned short u) {
    union { unsigned int i; float f; } v; v.i = ((unsigned int)u) << 16; return v.f;
}
__device__ __forceinline__ unsigned short f2bf(float f) {
    union { float f; unsigned int i; } v; v.f = f;
    unsigned int r = v.i + 0x7FFFu + ((v.i >> 16) & 1u);
    return (unsigned short)(r >> 16);
}

// ---------------------------------------------------------------------------
// prep: blocks [0,1024): x fp32 [b][k][p] -> x_hi/x_lo bf16 [b][p][k];
// blocks [1024,1152): weight hi/lo casts + zero plane regions.
// ---------------------------------------------------------------------------
__global__ __launch_bounds__(256) void prep_kernel(
    const float* __restrict__ x,
    const float* __restrict__ w_phi,
    const float* __restrict__ w_theta,
    const float* __restrict__ w_g,
    const float* __restrict__ w_mask,
    unsigned short* __restrict__ x_hi,
    unsigned short* __restrict__ x_lo,
    unsigned short* __restrict__ w3_hi,
    unsigned short* __restrict__ w3_lo,
    unsigned short* __restrict__ wm_hi,
    unsigned short* __restrict__ wm_lo,
    uint4* __restrict__ zero_region)
{
    const int tid = threadIdx.x;
    const int bx = blockIdx.x;

    if (bx < 1024) {
        const int b  = bx >> 8;
        const int kt = (bx >> 6) & 3;
        const int pt = bx & 63;
        __shared__ float tile[64][65];
        #pragma unroll
        for (int i = 0; i < 16; ++i) {
            int lin = tid + i * 256;
            int kk = lin >> 6, pp = lin & 63;
            tile[kk][pp] = x[(b * 256 + kt * 64 + kk) * 4096 + pt * 64 + pp];
        }
        __syncthreads();
        #pragma unroll
        for (int i = 0; i < 16; ++i) {
            int lin = tid + i * 256;
            int pp = lin >> 6, kk = lin & 63;
            float f = tile[kk][pp];
            unsigned short h = f2bf(f);
            int idx = (b * 4096 + pt * 64 + pp) * 256 + kt * 64 + kk;
            x_hi[idx] = h;
            x_lo[idx] = f2bf(f - bf2f(h));
        }
    } else {
        const int wid = (bx - 1024) * 256 + tid;   // 0..32767
        for (int e = wid; e < 98304; e += 32768) {
            int n = e >> 8, k = e & 255;
            float v = (n < 128) ? w_phi[n * 256 + k]
                    : (n < 256) ? w_theta[(n - 128) * 256 + k]
                                : w_g[(n - 256) * 256 + k];
            unsigned short h = f2bf(v);
            w3_hi[e] = h;
            w3_lo[e] = f2bf(v - bf2f(h));
        }
        {
            float v = w_mask[wid];
            unsigned short h = f2bf(v);
            wm_hi[wid] = h;
            wm_lo[wid] = f2bf(v - bf2f(h));
        }
        const uint4 z = make_uint4(0u, 0u, 0u, 0u);
        for (int i = wid; i < 645120; i += 32768) zero_region[i] = z;
    }
}

// ---------------------------------------------------------------------------
// conv3_mfma: D[n][p] = sum_k W3[n][k] x[k][p] with hi/lo split operands.
// 64(n) x 64(p) tile per block; wave w: n rows [nt*64+w*16, +16).
// ---------------------------------------------------------------------------
__global__ __launch_bounds__(256) void conv3_mfma_kernel(
    const unsigned short* __restrict__ x_hi,
    const unsigned short* __restrict__ x_lo,
    const unsigned short* __restrict__ w3_hi,
    const unsigned short* __restrict__ w3_lo,
    unsigned short* __restrict__ A_phi,
    unsigned short* __restrict__ theta_bf,
    unsigned short* __restrict__ A_g)
{
    const int tid = threadIdx.x;
    const int w   = tid >> 6;
    const int ln  = tid & 63;
    const int lm  = ln & 15;
    const int quad = ln >> 4;
    const int bx = blockIdx.x;   // px tile (64); py = bx
    const int nt = blockIdx.y;   // 0..5
    const int b  = blockIdx.z;
    const int n0 = nt * 64 + w * 16;

    const int arow = (n0 + lm) * 256 + quad * 8;
    const int brow = (b * 4096 + bx * 64 + lm) * 256 + quad * 8;

    floatx4 acc0 = {0.f, 0.f, 0.f, 0.f};
    floatx4 acc1 = {0.f, 0.f, 0.f, 0.f};
    floatx4 acc2 = {0.f, 0.f, 0.f, 0.f};
    floatx4 acc3 = {0.f, 0.f, 0.f, 0.f};

    #pragma unroll
    for (int k0 = 0; k0 < 256; k0 += 32) {
        short8 ah = *reinterpret_cast<const short8*>(w3_hi + arow + k0);
        short8 al = *reinterpret_cast<const short8*>(w3_lo + arow + k0);
        short8 bh0 = *reinterpret_cast<const short8*>(x_hi + brow + k0);
        short8 bh1 = *reinterpret_cast<const short8*>(x_hi + brow + 16 * 256 + k0);
        short8 bh2 = *reinterpret_cast<const short8*>(x_hi + brow + 32 * 256 + k0);
        short8 bh3 = *reinterpret_cast<const short8*>(x_hi + brow + 48 * 256 + k0);
        short8 bl0 = *reinterpret_cast<const short8*>(x_lo + brow + k0);
        short8 bl1 = *reinterpret_cast<const short8*>(x_lo + brow + 16 * 256 + k0);
        short8 bl2 = *reinterpret_cast<const short8*>(x_lo + brow + 32 * 256 + k0);
        short8 bl3 = *reinterpret_cast<const short8*>(x_lo + brow + 48 * 256 + k0);
        acc0 = __builtin_amdgcn_mfma_f32_16x16x32_bf16(ah, bh0, acc0, 0, 0, 0);
        acc1 = __builtin_amdgcn_mfma_f32_16x16x32_bf16(ah, bh1, acc1, 0, 0, 0);
        acc2 = __builtin_amdgcn_mfma_f32_16x16x32_bf16(ah, bh2, acc2, 0, 0, 0);
        acc3 = __builtin_amdgcn_mfma_f32_16x16x32_bf16(ah, bh3, acc3, 0, 0, 0);
        acc0 = __builtin_amdgcn_mfma_f32_16x16x32_bf16(ah, bl0, acc0, 0, 0, 0);
        acc1 = __builtin_amdgcn_mfma_f32_16x16x32_bf16(ah, bl1, acc1, 0, 0, 0);
        acc2 = __builtin_amdgcn_mfma_f32_16x16x32_bf16(ah, bl2, acc2, 0, 0, 0);
        acc3 = __builtin_amdgcn_mfma_f32_16x16x32_bf16(ah, bl3, acc3, 0, 0, 0);
        acc0 = __builtin_amdgcn_mfma_f32_16x16x32_bf16(al, bh0, acc0, 0, 0, 0);
        acc1 = __builtin_amdgcn_mfma_f32_16x16x32_bf16(al, bh1, acc1, 0, 0, 0);
        acc2 = __builtin_amdgcn_mfma_f32_16x16x32_bf16(al, bh2, acc2, 0, 0, 0);
        acc3 = __builtin_amdgcn_mfma_f32_16x16x32_bf16(al, bh3, acc3, 0, 0, 0);
    }

    floatx4 accs[4] = {acc0, acc1, acc2, acc3};
    const int py = bx;
    if (nt == 2 || nt == 3) {
        #pragma unroll
        for (int ct = 0; ct < 4; ++ct) {
            const int p = bx * 64 + ct * 16 + lm;
            #pragma unroll
            for (int reg = 0; reg < 4; ++reg) {
                const int n = n0 + quad * 4 + reg;
                theta_bf[(b * 4096 + p) * 128 + (n - 128)] = f2bf(accs[ct][reg]);
            }
        }
    } else {
        unsigned short* __restrict__ A = (nt < 2) ? A_phi : A_g;
        const int nbias = (nt < 2) ? 0 : 256;
        #pragma unroll
        for (int ct = 0; ct < 4; ++ct) {
            const int pxx = ct * 16 + lm;
            #pragma unroll
            for (int reg = 0; reg < 4; ++reg) {
                const int pl = n0 + quad * 4 + reg - nbias;
                A[b * A_BATCH + pl * PLANE + (py + 3) * 72 + pxx + 4] =
                    f2bf(accs[ct][reg]);
            }
        }
    }
}

// ---------------------------------------------------------------------------
// scores: wave per pixel s, lane = t. 3 pure + 2 mixed cc-segments over
// padded phi planes. scores fp32 slots [b][s][64] (first 49 used).
// ---------------------------------------------------------------------------
__global__ __launch_bounds__(256) void scores_kernel(
    const unsigned short* __restrict__ Apad,
    const unsigned short* __restrict__ theta_bf,
    float* __restrict__ scores)
{
    const int w  = threadIdx.x >> 6;
    const int ln = threadIdx.x & 63;
    const int s  = blockIdx.x * 4 + w;
    const int b  = blockIdx.y;

    __shared__ float th[4][128];
    {
        const unsigned short* tb = theta_bf + (b * 4096 + s) * 128;
        th[w][ln]      = bf2f(tb[ln]);
        th[w][ln + 64] = bf2f(tb[ln + 64]);
    }
    __syncthreads();

    const unsigned short* __restrict__ Ab = Apad + b * A_BATCH;

    const int base  = s * 6272;
    const int ch_lo = base >> 12;
    const unsigned B1 = (unsigned)(ch_lo + 1) << 12;
    const unsigned B2 = (unsigned)(ch_lo + 2) << 12;
    const int d1 = (int)B1 - base;
    const int d2 = d1 + 4096;

    int A1 = d1 / 49;
    int A2 = (d1 + 48) / 49;
    int C1 = d2 / 49;        if (C1 > 128) C1 = 128;
    int C2 = (d2 + 48) / 49; if (C2 > 128) C2 = 128;

    unsigned OFFv[3];
    #pragma unroll
    for (int i = 0; i < 3; ++i) {
        int ch = ch_lo + i;
        int c0 = ch / 49; if (c0 > 127) c0 = 127;
        int rr = ch - c0 * 49;
        int kh = rr / 7;
        int kw = rr - kh * 7;
        OFFv[i] = (unsigned)(c0 * PLANE + kh * 72 + kw + 1);
    }

    unsigned F = (unsigned)(base + ln);
    float acc = 0.f;

    {
        const unsigned OFF_ = OFFv[0];
        #pragma unroll 4
        for (int cc = 0; cc < A1; ++cc) {
            unsigned p = F & 4095u;
            unsigned a = OFF_ + p + ((p >> 6) << 3);
            acc = fmaf(th[w][cc], bf2f(Ab[a]), acc);
            F += 49u;
        }
    }
    for (int cc = A1; cc < A2; ++cc) {
        unsigned OFF_ = (F >= B1) ? OFFv[1] : OFFv[0];
        unsigned p = F & 4095u;
        unsigned a = OFF_ + p + ((p >> 6) << 3);
        acc = fmaf(th[w][cc], bf2f(Ab[a]), acc);
        F += 49u;
    }
    {
        const unsigned OFF_ = OFFv[1];
        #pragma unroll 4
        for (int cc = A2; cc < C1; ++cc) {
            unsigned p = F & 4095u;
            unsigned a = OFF_ + p + ((p >> 6) << 3);
            acc = fmaf(th[w][cc], bf2f(Ab[a]), acc);
            F += 49u;
        }
    }
    for (int cc = C1; cc < C2; ++cc) {
        unsigned OFF_ = (F >= B2) ? OFFv[2] : OFFv[1];
        unsigned p = F & 4095u;
        unsigned a = OFF_ + p + ((p >> 6) << 3);
        acc = fmaf(th[w][cc], bf2f(Ab[a]), acc);
        F += 49u;
    }
    {
        const unsigned OFF_ = OFFv[2];
        #pragma unroll 4
        for (int cc = C2; cc < 128; ++cc) {
            unsigned p = F & 4095u;
            unsigned a = OFF_ + p + ((p >> 6) << 3);
            acc = fmaf(th[w][cc], bf2f(Ab[a]), acc);
            F += 49u;
        }
    }

    if (ln < 49) scores[(b * 4096 + s) * 64 + ln] = acc;
}

// ---------------------------------------------------------------------------
// softmax over h (axis=1): block per (b,j); LDS-transpose 64(i) x 49(t).
// ---------------------------------------------------------------------------
__global__ __launch_bounds__(256) void softmax_kernel(float* __restrict__ scores)
{
    const int b = blockIdx.x >> 6;
    const int j = blockIdx.x & 63;
    const int tid = threadIdx.x;
    const int wv = tid >> 6;
    const int ln = tid & 63;

    __shared__ float tile[64][52];
    __shared__ float inv[52];

    #pragma unroll
    for (int it = 0; it < 16; ++it) {
        int i = it * 4 + wv;
        if (ln < 49) tile[i][ln] = scores[(b * 4096 + i * 64 + j) * 64 + ln];
    }
    __syncthreads();

    if (tid < 49) {
        float m = -3.4e38f;
        #pragma unroll 8
        for (int i = 0; i < 64; ++i) m = fmaxf(m, tile[i][tid]);
        float sum = 0.f;
        #pragma unroll 8
        for (int i = 0; i < 64; ++i) {
            float e = __expf(tile[i][tid] - m);
            tile[i][tid] = e;
            sum += e;
        }
        inv[tid] = 1.f / sum;
    }
    __syncthreads();

    #pragma unroll
    for (int it = 0; it < 16; ++it) {
        int i = it * 4 + wv;
        if (ln < 49) scores[(b * 4096 + i * 64 + j) * 64 + ln] = tile[i][ln] * inv[ln];
    }
}

// ---------------------------------------------------------------------------
// aggregate: 2 pixels/block, lane = cc (128). Segment trick over t.
// y bf16 [b][s][cc] to ws.
// ---------------------------------------------------------------------------
__global__ __launch_bounds__(256) void aggregate_kernel(
    const float* __restrict__ scores,
    const unsigned short* __restrict__ Apad,
    unsigned short* __restrict__ y_bf)
{
    const int pix = threadIdx.x >> 7;
    const int cc  = threadIdx.x & 127;
    const int s   = blockIdx.x * 2 + pix;
    const int b   = blockIdx.y;

    __shared__ float at[2][52];
    if (cc < 49) at[pix][cc] = scores[(b * 4096 + s) * 64 + cc];
    __syncthreads();

    const unsigned short* __restrict__ Ab = Apad + b * A_BATCH;

    const int base  = s * 6272;
    const int ch_lo = base >> 12;
    const unsigned B1 = (unsigned)(ch_lo + 1) << 12;
    const unsigned B2 = (unsigned)(ch_lo + 2) << 12;
    const int d1 = (int)B1 - base;
    const int d2 = d1 + 4096;

    int A1 = d1 >> 7;
    int A2 = (d1 + 127) >> 7;
    int C1 = d2 >> 7;          if (C1 > 49) C1 = 49;
    int C2 = (d2 + 127) >> 7;  if (C2 > 49) C2 = 49;
    if (A1 > 49) A1 = 49;
    if (A2 > 49) A2 = 49;

    unsigned OFFv[3];
    #pragma unroll
    for (int i = 0; i < 3; ++i) {
        int ch = ch_lo + i;
        int c0 = ch / 49; if (c0 > 127) c0 = 127;
        int rr = ch - c0 * 49;
        int kh = rr / 7;
        int kw = rr - kh * 7;
        OFFv[i] = (unsigned)(c0 * PLANE + kh * 72 + kw + 1);
    }

    unsigned F = (unsigned)(base + cc);
    float acc = 0.f;

    {
        const unsigned OFF_ = OFFv[0];
        #pragma unroll 4
        for (int t = 0; t < A1; ++t) {
            unsigned p = F & 4095u;
            unsigned a = OFF_ + p + ((p >> 6) << 3);
            acc = fmaf(at[pix][t], bf2f(Ab[a]), acc);
            F += 128u;
        }
    }
    for (int t = A1; t < A2; ++t) {
        unsigned OFF_ = (F >= B1) ? OFFv[1] : OFFv[0];
        unsigned p = F & 4095u;
        unsigned a = OFF_ + p + ((p >> 6) << 3);
        acc = fmaf(at[pix][t], bf2f(Ab[a]), acc);
        F += 128u;
    }
    {
        const unsigned OFF_ = OFFv[1];
        #pragma unroll 4
        for (int t = A2; t < C1; ++t) {
            unsigned p = F & 4095u;
            unsigned a = OFF_ + p + ((p >> 6) << 3);
            acc = fmaf(at[pix][t], bf2f(Ab[a]), acc);
            F += 128u;
        }
    }
    for (int t = C1; t < C2; ++t) {
        unsigned OFF_ = (F >= B2) ? OFFv[2] : OFFv[1];
        unsigned p = F & 4095u;
        unsigned a = OFF_ + p + ((p >> 6) << 3);
        acc = fmaf(at[pix][t], bf2f(Ab[a]), acc);
        F += 128u;
    }
    {
        const unsigned OFF_ = OFFv[2];
        for (int t = C2; t < 49; ++t) {
            unsigned p = F & 4095u;
            unsigned a = OFF_ + p + ((p >> 6) << 3);
            acc = fmaf(at[pix][t], bf2f(Ab[a]), acc);
            F += 128u;
        }
    }

    y_bf[(b * 4096 + s) * 128 + cc] = f2bf(acc);
}

// ---------------------------------------------------------------------------
// maskconv_mfma: out[b,o,p] = x[b,o,p] + sum_cc wm[o,cc] y[p,cc].
// wm split hi/lo (2 MFMAs/pair); y bf16 as-is. 64x64 tile, K=128.
// ---------------------------------------------------------------------------
__global__ __launch_bounds__(256) void maskconv_mfma_kernel(
    const float* __restrict__ x,
    const unsigned short* __restrict__ wm_hi,
    const unsigned short* __restrict__ wm_lo,
    const unsigned short* __restrict__ y_bf,
    float* __restrict__ out)
{
    const int tid = threadIdx.x;
    const int w   = tid >> 6;
    const int ln  = tid & 63;
    const int lm  = ln & 15;
    const int quad = ln >> 4;
    const int bx = blockIdx.x;   // px tile (64)
    const int ot = blockIdx.y;   // 0..3
    const int b  = blockIdx.z;
    const int o0 = ot * 64 + w * 16;

    const int arow = (o0 + lm) * 128 + quad * 8;
    const unsigned short* __restrict__ Brow =
        y_bf + (b * 4096 + bx * 64 + lm) * 128 + quad * 8;

    floatx4 acc0 = {0.f, 0.f, 0.f, 0.f};
    floatx4 acc1 = {0.f, 0.f, 0.f, 0.f};
    floatx4 acc2 = {0.f, 0.f, 0.f, 0.f};
    floatx4 acc3 = {0.f, 0.f, 0.f, 0.f};

    #pragma unroll
    for (int k0 = 0; k0 < 128; k0 += 32) {
        short8 ah = *reinterpret_cast<const short8*>(wm_hi + arow + k0);
        short8 al = *reinterpret_cast<const short8*>(wm_lo + arow + k0);
        short8 b0 = *reinterpret_cast<const short8*>(Brow + k0);
        short8 b1 = *reinterpret_cast<const short8*>(Brow + 16 * 128 + k0);
        short8 b2 = *reinterpret_cast<const short8*>(Brow + 32 * 128 + k0);
        short8 b3 = *reinterpret_cast<const short8*>(Brow + 48 * 128 + k0);
        acc0 = __builtin_amdgcn_mfma_f32_16x16x32_bf16(ah, b0, acc0, 0, 0, 0);
        acc1 = __builtin_amdgcn_mfma_f32_16x16x32_bf16(ah, b1, acc1, 0, 0, 0);
        acc2 = __builtin_amdgcn_mfma_f32_16x16x32_bf16(ah, b2, acc2, 0, 0, 0);
        acc3 = __builtin_amdgcn_mfma_f32_16x16x32_bf16(ah, b3, acc3, 0, 0, 0);
        acc0 = __builtin_amdgcn_mfma_f32_16x16x32_bf16(al, b0, acc0, 0, 0, 0);
        acc1 = __builtin_amdgcn_mfma_f32_16x16x32_bf16(al, b1, acc1, 0, 0, 0);
        acc2 = __builtin_amdgcn_mfma_f32_16x16x32_bf16(al, b2, acc2, 0, 0, 0);
        acc3 = __builtin_amdgcn_mfma_f32_16x16x32_bf16(al, b3, acc3, 0, 0, 0);
    }

    floatx4 accs[4] = {acc0, acc1, acc2, acc3};
    #pragma unroll
    for (int ct = 0; ct < 4; ++ct) {
        const int p = bx * 64 + ct * 16 + lm;
        #pragma unroll
        for (int reg = 0; reg < 4; ++reg) {
            const int o = o0 + quad * 4 + reg;
            const int ofs = (b * 256 + o) * 4096 + p;
            out[ofs] = accs[ct][reg] + x[ofs];
        }
    }
}

extern "C" void kernel_launch(void* const* d_in, const int* in_sizes, int n_in,
                              void* d_out, int out_size, void* d_ws, size_t ws_size,
                              hipStream_t stream) {
    const float* x       = (const float*)d_in[0];
    const float* w_phi   = (const float*)d_in[1];
    const float* w_theta = (const float*)d_in[2];
    const float* w_g     = (const float*)d_in[3];
    const float* w_mask  = (const float*)d_in[4];

    float* out_f = (float*)d_out;

    unsigned short* ws_u  = (unsigned short*)d_ws;
    unsigned short* A_phi = ws_u;                      // 2,580,480 ush
    unsigned short* A_g   = ws_u + 2580480;            // 2,580,480 ush
    unsigned short* y_u   = ws_u + 5160960;            // 2,097,152 ush
    unsigned short* th_u  = ws_u + 7258112;            // 2,097,152 ush
    float*          sc_f  = (float*)(ws_u + 9355264);  // 1,048,576 fp32
    unsigned short* xh_u  = ws_u + 11452416;           // 4,194,304 ush
    unsigned short* xl_u  = ws_u + 15646720;           // 4,194,304 ush
    unsigned short* w3h_u = ws_u + 19841024;           // 98,304 ush
    unsigned short* w3l_u = ws_u + 19939328;           // 98,304 ush
    unsigned short* wmh_u = ws_u + 20037632;           // 32,768 ush
    unsigned short* wml_u = ws_u + 20070400;           // 32,768 ush

    // 1: prep (x transpose + hi/lo split, weight splits, zero planes)
    hipLaunchKernelGGL(prep_kernel, dim3(1152), dim3(256), 0, stream,
                       x, w_phi, w_theta, w_g, w_mask,
                       xh_u, xl_u, w3h_u, w3l_u, wmh_u, wml_u, (uint4*)A_phi);
    // 2: conv3 via split-bf16 MFMA
    hipLaunchKernelGGL(conv3_mfma_kernel, dim3(64, 6, 4), dim3(256), 0, stream,
                       xh_u, xl_u, w3h_u, w3l_u, A_phi, th_u, A_g);
    // 3: scores
    hipLaunchKernelGGL(scores_kernel, dim3(1024, 4), dim3(256), 0, stream,
                       A_phi, th_u, sc_f);
    // 4: softmax over h
    hipLaunchKernelGGL(softmax_kernel, dim3(256), dim3(256), 0, stream, sc_f);
    // 5: aggregate -> y bf16
    hipLaunchKernelGGL(aggregate_kernel, dim3(2048, 4), dim3(256), 0, stream,
                       sc_f, A_g, y_u);
    // 6: maskconv via split-w MFMA + residual -> out
    hipLaunchKernelGGL(maskconv_mfma_kernel, dim3(64, 4, 4), dim3(256), 0, stream,
                       x, wmh_u, wml_u, y_u, out_f);
}

// Round 11
// 181.907 us; speedup vs baseline: 1.6296x; 1.2406x over previous
//
#include <hip/hip_runtime.h>

// Problem: b=4, c=256, ci=128, h=w=64 (HW=4096), field=7, kk=49. fp32 I/O.
//
// 6-dispatch pipeline; MFMA GEMMs (split-bf16 hi+lo) with operands PACKED in
// MFMA-fragment order so every load is one coalesced 1 KB transaction:
//   fragment = 512 ushorts; lane ln reads 16 B at frag_base + ln*16.
//   B-frag value convention (r10-verified): elem[ln*8+j] = M[k=( ln>>4 )*8+j]
//   [col = (ln&15)]; A-frag: elem[ln*8+j] = W[row=(ln&15)][k=(ln>>4)*8+j].
//  1. prep: x -> xp_hi/lo packed [b][kb8][pt16:256][512]; w3 -> w3p_hi/lo
//     [nt16:24][kb8][512]; wm -> wmp_hi/lo [ot16:16][kb4][512]; zero planes.
//  2. conv3_mfma: acc += Ahi.Bhi + Ahi.Blo + Alo.Bhi; epilogue: phi/g ->
//     padded planes, theta -> [p][cc] bf16 (all r9/r10-verified).
//  3. scores: segmented flat-decode gather (verified r6-10).
//  4. softmax over h per (b,j) (verified).
//  5. aggregate: segmented gather; y stored PACKED [b][kb4][pt16][512].
//  6. maskconv_mfma: (wm_hi+wm_lo).y + x -> out fp32.
//
// Padded planes: [b][c0][70][72] bf16, data (py,px) at (py+3,px+4), zero
// borders; patch addr for F -> (ch=F>>12, p=F&4095):
//   a = OFF(ch) + p + 8*(p>>6), OFF(ch) = c0*5040 + kh*72 + kw + 1.
// Per-pixel F-range < 2*4096 -> <=3 ch values -> 3 pure + 2 mixed segments.
//
// ws layout (ushort units):
//   A_phi  @ 0          (2,580,480)
//   A_g    @ 2,580,480  (2,580,480)   (zeroed contiguously with A_phi)
//   y_p    @ 5,160,960  (2,097,152)   packed
//   theta  @ 7,258,112  (2,097,152)
//   scores @ 9,355,264  (2,097,152 ush = 1,048,576 fp32)
//   xp_hi  @ 11,452,416 (4,194,304)
//   xp_lo  @ 15,646,720 (4,194,304)
//   w3p_hi @ 19,841,024 (98,304)
//   w3p_lo @ 19,939,328 (98,304)
//   wmp_hi @ 20,037,632 (32,768)
//   wmp_lo @ 20,070,400 (32,768)     => ~40.2 MB total

#define PLANE    5040
#define A_BATCH  645120

typedef __attribute__((ext_vector_type(8))) short short8;
typedef __attribute__((ext_vector_type(4))) float floatx4;

__device__ __forceinline__ float bf2f(unsigned short u) {
    union { unsigned int i; float f; } v; v.i = ((unsigned int)u) << 16; return v.f;
}
__device__ __forceinline__ unsigned short f2bf(float f) {
    union { float f; unsigned int i; } v; v.f = f;
    unsigned int r = v.i + 0x7FFFu + ((v.i >> 16) & 1u);
    return (unsigned short)(r >> 16);
}

// ---------------------------------------------------------------------------
// prep: blocks [0,1024): x fp32 [b][k][p] -> packed hi/lo fragments.
// blocks [1024,1152): w3p/wmp hi/lo packed casts + zero plane regions.
// ---------------------------------------------------------------------------
__global__ __launch_bounds__(256) void prep_kernel(
    const float* __restrict__ x,
    const float* __restrict__ w_phi,
    const float* __restrict__ w_theta,
    const float* __restrict__ w_g,
    const float* __restrict__ w_mask,
    unsigned short* __restrict__ xp_hi,
    unsigned short* __restrict__ xp_lo,
    unsigned short* __restrict__ w3p_hi,
    unsigned short* __restrict__ w3p_lo,
    unsigned short* __restrict__ wmp_hi,
    unsigned short* __restrict__ wmp_lo,
    uint4* __restrict__ zero_region)
{
    const int tid = threadIdx.x;
    const int bx = blockIdx.x;

    if (bx < 1024) {
        const int b  = bx >> 8;          // batch
        const int kt = (bx >> 6) & 3;    // k 64-tile
        const int pt = bx & 63;          // p 64-tile
        __shared__ float tile[64][65];   // [k][p]
        #pragma unroll
        for (int i = 0; i < 16; ++i) {
            int lin = tid + i * 256;
            int kk = lin >> 6, pp = lin & 63;
            tile[kk][pp] = x[(b * 256 + kt * 64 + kk) * 4096 + pt * 64 + pp];
        }
        __syncthreads();
        // write 8 fragments (2 kb x 4 pt16), fully coalesced
        #pragma unroll
        for (int i = 0; i < 16; ++i) {
            int lin = tid + i * 256;
            int frag = lin >> 9;          // 0..7
            int idx  = lin & 511;
            int kbL  = frag >> 2;         // 0..1
            int ptL  = frag & 3;          // 0..3
            int j    = idx & 7;
            int n    = (idx >> 3) & 15;
            int quad = idx >> 7;
            float f = tile[kbL * 32 + quad * 8 + j][ptL * 16 + n];
            unsigned short h = f2bf(f);
            int addr = ((b * 8 + kt * 2 + kbL) * 256 + pt * 4 + ptL) * 512 + idx;
            xp_hi[addr] = h;
            xp_lo[addr] = f2bf(f - bf2f(h));
        }
    } else {
        const int wid = (bx - 1024) * 256 + tid;   // 0..32767
        // w3p: packed addr e -> (nt16, kb, quad, m, j) -> source (n,k)
        for (int e = wid; e < 98304; e += 32768) {
            int frag = e >> 9;            // 0..191
            int idx  = e & 511;
            int nt16 = frag >> 3, kb = frag & 7;
            int j = idx & 7, m = (idx >> 3) & 15, quad = idx >> 7;
            int n = nt16 * 16 + m;
            int k = kb * 32 + quad * 8 + j;
            float v = (n < 128) ? w_phi[n * 256 + k]
                    : (n < 256) ? w_theta[(n - 128) * 256 + k]
                                : w_g[(n - 256) * 256 + k];
            unsigned short h = f2bf(v);
            w3p_hi[e] = h;
            w3p_lo[e] = f2bf(v - bf2f(h));
        }
        {
            int e = wid;                  // 0..32767 exactly covers wmp
            int frag = e >> 9;            // 0..63
            int idx  = e & 511;
            int ot16 = frag >> 2, kb = frag & 3;
            int j = idx & 7, m = (idx >> 3) & 15, quad = idx >> 7;
            float v = w_mask[(ot16 * 16 + m) * 128 + kb * 32 + quad * 8 + j];
            unsigned short h = f2bf(v);
            wmp_hi[e] = h;
            wmp_lo[e] = f2bf(v - bf2f(h));
        }
        const uint4 z = make_uint4(0u, 0u, 0u, 0u);
        for (int i = wid; i < 645120; i += 32768) zero_region[i] = z;
    }
}

// ---------------------------------------------------------------------------
// conv3_mfma: D[n][p] = sum_k W3[n][k] x[k][p], split hi/lo (3 MFMAs/pair).
// Block (bx=px 64-tile, nt 0..5, b); wave w: n rows [nt*64+w*16, +16).
// All loads are packed-fragment (1 KB coalesced).
// ---------------------------------------------------------------------------
__global__ __launch_bounds__(256) void conv3_mfma_kernel(
    const unsigned short* __restrict__ xp_hi,
    const unsigned short* __restrict__ xp_lo,
    const unsigned short* __restrict__ w3p_hi,
    const unsigned short* __restrict__ w3p_lo,
    unsigned short* __restrict__ A_phi,
    unsigned short* __restrict__ theta_bf,
    unsigned short* __restrict__ A_g)
{
    const int tid = threadIdx.x;
    const int w   = tid >> 6;
    const int ln  = tid & 63;
    const int lm  = ln & 15;
    const int quad = ln >> 4;
    const int bx = blockIdx.x;   // px 64-tile; py = bx
    const int nt = blockIdx.y;   // 0..5
    const int b  = blockIdx.z;
    const int nt16 = nt * 4 + w;
    const int lnofs = ln * 8;

    floatx4 acc0 = {0.f, 0.f, 0.f, 0.f};
    floatx4 acc1 = {0.f, 0.f, 0.f, 0.f};
    floatx4 acc2 = {0.f, 0.f, 0.f, 0.f};
    floatx4 acc3 = {0.f, 0.f, 0.f, 0.f};

    #pragma unroll
    for (int kb = 0; kb < 8; ++kb) {
        const int aoff = (nt16 * 8 + kb) * 512 + lnofs;
        const int boff = ((b * 8 + kb) * 256 + bx * 4) * 512 + lnofs;
        short8 ah = *reinterpret_cast<const short8*>(w3p_hi + aoff);
        short8 al = *reinterpret_cast<const short8*>(w3p_lo + aoff);
        short8 bh0 = *reinterpret_cast<const short8*>(xp_hi + boff);
        short8 bh1 = *reinterpret_cast<const short8*>(xp_hi + boff + 512);
        short8 bh2 = *reinterpret_cast<const short8*>(xp_hi + boff + 1024);
        short8 bh3 = *reinterpret_cast<const short8*>(xp_hi + boff + 1536);
        short8 bl0 = *reinterpret_cast<const short8*>(xp_lo + boff);
        short8 bl1 = *reinterpret_cast<const short8*>(xp_lo + boff + 512);
        short8 bl2 = *reinterpret_cast<const short8*>(xp_lo + boff + 1024);
        short8 bl3 = *reinterpret_cast<const short8*>(xp_lo + boff + 1536);
        acc0 = __builtin_amdgcn_mfma_f32_16x16x32_bf16(ah, bh0, acc0, 0, 0, 0);
        acc1 = __builtin_amdgcn_mfma_f32_16x16x32_bf16(ah, bh1, acc1, 0, 0, 0);
        acc2 = __builtin_amdgcn_mfma_f32_16x16x32_bf16(ah, bh2, acc2, 0, 0, 0);
        acc3 = __builtin_amdgcn_mfma_f32_16x16x32_bf16(ah, bh3, acc3, 0, 0, 0);
        acc0 = __builtin_amdgcn_mfma_f32_16x16x32_bf16(ah, bl0, acc0, 0, 0, 0);
        acc1 = __builtin_amdgcn_mfma_f32_16x16x32_bf16(ah, bl1, acc1, 0, 0, 0);
        acc2 = __builtin_amdgcn_mfma_f32_16x16x32_bf16(ah, bl2, acc2, 0, 0, 0);
        acc3 = __builtin_amdgcn_mfma_f32_16x16x32_bf16(ah, bl3, acc3, 0, 0, 0);
        acc0 = __builtin_amdgcn_mfma_f32_16x16x32_bf16(al, bh0, acc0, 0, 0, 0);
        acc1 = __builtin_amdgcn_mfma_f32_16x16x32_bf16(al, bh1, acc1, 0, 0, 0);
        acc2 = __builtin_amdgcn_mfma_f32_16x16x32_bf16(al, bh2, acc2, 0, 0, 0);
        acc3 = __builtin_amdgcn_mfma_f32_16x16x32_bf16(al, bh3, acc3, 0, 0, 0);
    }

    floatx4 accs[4] = {acc0, acc1, acc2, acc3};
    const int n0 = nt16 * 16;
    const int py = bx;
    if (nt == 2 || nt == 3) {
        #pragma unroll
        for (int ct = 0; ct < 4; ++ct) {
            const int p = bx * 64 + ct * 16 + lm;
            #pragma unroll
            for (int reg = 0; reg < 4; ++reg) {
                const int n = n0 + quad * 4 + reg;
                theta_bf[(b * 4096 + p) * 128 + (n - 128)] = f2bf(accs[ct][reg]);
            }
        }
    } else {
        unsigned short* __restrict__ A = (nt < 2) ? A_phi : A_g;
        const int nbias = (nt < 2) ? 0 : 256;
        #pragma unroll
        for (int ct = 0; ct < 4; ++ct) {
            const int pxx = ct * 16 + lm;
            #pragma unroll
            for (int reg = 0; reg < 4; ++reg) {
                const int pl = n0 + quad * 4 + reg - nbias;
                A[b * A_BATCH + pl * PLANE + (py + 3) * 72 + pxx + 4] =
                    f2bf(accs[ct][reg]);
            }
        }
    }
}

// ---------------------------------------------------------------------------
// scores: wave per pixel s, lane = t. 3 pure + 2 mixed cc-segments over
// padded phi planes. scores fp32 slots [b][s][64] (first 49 used).
// ---------------------------------------------------------------------------
__global__ __launch_bounds__(256) void scores_kernel(
    const unsigned short* __restrict__ Apad,
    const unsigned short* __restrict__ theta_bf,
    float* __restrict__ scores)
{
    const int w  = threadIdx.x >> 6;
    const int ln = threadIdx.x & 63;
    const int s  = blockIdx.x * 4 + w;
    const int b  = blockIdx.y;

    __shared__ float th[4][128];
    {
        const unsigned short* tb = theta_bf + (b * 4096 + s) * 128;
        th[w][ln]      = bf2f(tb[ln]);
        th[w][ln + 64] = bf2f(tb[ln + 64]);
    }
    __syncthreads();

    const unsigned short* __restrict__ Ab = Apad + b * A_BATCH;

    const int base  = s * 6272;
    const int ch_lo = base >> 12;
    const unsigned B1 = (unsigned)(ch_lo + 1) << 12;
    const unsigned B2 = (unsigned)(ch_lo + 2) << 12;
    const int d1 = (int)B1 - base;
    const int d2 = d1 + 4096;

    int A1 = d1 / 49;
    int A2 = (d1 + 48) / 49;
    int C1 = d2 / 49;        if (C1 > 128) C1 = 128;
    int C2 = (d2 + 48) / 49; if (C2 > 128) C2 = 128;

    unsigned OFFv[3];
    #pragma unroll
    for (int i = 0; i < 3; ++i) {
        int ch = ch_lo + i;
        int c0 = ch / 49; if (c0 > 127) c0 = 127;
        int rr = ch - c0 * 49;
        int kh = rr / 7;
        int kw = rr - kh * 7;
        OFFv[i] = (unsigned)(c0 * PLANE + kh * 72 + kw + 1);
    }

    unsigned F = (unsigned)(base + ln);
    float acc = 0.f;

    {
        const unsigned OFF_ = OFFv[0];
        #pragma unroll 4
        for (int cc = 0; cc < A1; ++cc) {
            unsigned p = F & 4095u;
            unsigned a = OFF_ + p + ((p >> 6) << 3);
            acc = fmaf(th[w][cc], bf2f(Ab[a]), acc);
            F += 49u;
        }
    }
    for (int cc = A1; cc < A2; ++cc) {
        unsigned OFF_ = (F >= B1) ? OFFv[1] : OFFv[0];
        unsigned p = F & 4095u;
        unsigned a = OFF_ + p + ((p >> 6) << 3);
        acc = fmaf(th[w][cc], bf2f(Ab[a]), acc);
        F += 49u;
    }
    {
        const unsigned OFF_ = OFFv[1];
        #pragma unroll 4
        for (int cc = A2; cc < C1; ++cc) {
            unsigned p = F & 4095u;
            unsigned a = OFF_ + p + ((p >> 6) << 3);
            acc = fmaf(th[w][cc], bf2f(Ab[a]), acc);
            F += 49u;
        }
    }
    for (int cc = C1; cc < C2; ++cc) {
        unsigned OFF_ = (F >= B2) ? OFFv[2] : OFFv[1];
        unsigned p = F & 4095u;
        unsigned a = OFF_ + p + ((p >> 6) << 3);
        acc = fmaf(th[w][cc], bf2f(Ab[a]), acc);
        F += 49u;
    }
    {
        const unsigned OFF_ = OFFv[2];
        #pragma unroll 4
        for (int cc = C2; cc < 128; ++cc) {
            unsigned p = F & 4095u;
            unsigned a = OFF_ + p + ((p >> 6) << 3);
            acc = fmaf(th[w][cc], bf2f(Ab[a]), acc);
            F += 49u;
        }
    }

    if (ln < 49) scores[(b * 4096 + s) * 64 + ln] = acc;
}

// ---------------------------------------------------------------------------
// softmax over h (axis=1): block per (b,j); LDS-transpose 64(i) x 49(t).
// ---------------------------------------------------------------------------
__global__ __launch_bounds__(256) void softmax_kernel(float* __restrict__ scores)
{
    const int b = blockIdx.x >> 6;
    const int j = blockIdx.x & 63;
    const int tid = threadIdx.x;
    const int wv = tid >> 6;
    const int ln = tid & 63;

    __shared__ float tile[64][52];
    __shared__ float inv[52];

    #pragma unroll
    for (int it = 0; it < 16; ++it) {
        int i = it * 4 + wv;
        if (ln < 49) tile[i][ln] = scores[(b * 4096 + i * 64 + j) * 64 + ln];
    }
    __syncthreads();

    if (tid < 49) {
        float m = -3.4e38f;
        #pragma unroll 8
        for (int i = 0; i < 64; ++i) m = fmaxf(m, tile[i][tid]);
        float sum = 0.f;
        #pragma unroll 8
        for (int i = 0; i < 64; ++i) {
            float e = __expf(tile[i][tid] - m);
            tile[i][tid] = e;
            sum += e;
        }
        inv[tid] = 1.f / sum;
    }
    __syncthreads();

    #pragma unroll
    for (int it = 0; it < 16; ++it) {
        int i = it * 4 + wv;
        if (ln < 49) scores[(b * 4096 + i * 64 + j) * 64 + ln] = tile[i][ln] * inv[ln];
    }
}

// ---------------------------------------------------------------------------
// aggregate: 2 pixels/block, lane = cc (128). Segment trick over t.
// y stored PACKED: y_p[((b*4+kb)*256+pt16)*512 + (quad*16+n)*8 + j].
// ---------------------------------------------------------------------------
__global__ __launch_bounds__(256) void aggregate_kernel(
    const float* __restrict__ scores,
    const unsigned short* __restrict__ Apad,
    unsigned short* __restrict__ y_p)
{
    const int pix = threadIdx.x >> 7;
    const int cc  = threadIdx.x & 127;
    const int s   = blockIdx.x * 2 + pix;
    const int b   = blockIdx.y;

    __shared__ float at[2][52];
    if (cc < 49) at[pix][cc] = scores[(b * 4096 + s) * 64 + cc];
    __syncthreads();

    const unsigned short* __restrict__ Ab = Apad + b * A_BATCH;

    const int base  = s * 6272;
    const int ch_lo = base >> 12;
    const unsigned B1 = (unsigned)(ch_lo + 1) << 12;
    const unsigned B2 = (unsigned)(ch_lo + 2) << 12;
    const int d1 = (int)B1 - base;
    const int d2 = d1 + 4096;

    int A1 = d1 >> 7;
    int A2 = (d1 + 127) >> 7;
    int C1 = d2 >> 7;          if (C1 > 49) C1 = 49;
    int C2 = (d2 + 127) >> 7;  if (C2 > 49) C2 = 49;
    if (A1 > 49) A1 = 49;
    if (A2 > 49) A2 = 49;

    unsigned OFFv[3];
    #pragma unroll
    for (int i = 0; i < 3; ++i) {
        int ch = ch_lo + i;
        int c0 = ch / 49; if (c0 > 127) c0 = 127;
        int rr = ch - c0 * 49;
        int kh = rr / 7;
        int kw = rr - kh * 7;
        OFFv[i] = (unsigned)(c0 * PLANE + kh * 72 + kw + 1);
    }

    unsigned F = (unsigned)(base + cc);
    float acc = 0.f;

    {
        const unsigned OFF_ = OFFv[0];
        #pragma unroll 4
        for (int t = 0; t < A1; ++t) {
            unsigned p = F & 4095u;
            unsigned a = OFF_ + p + ((p >> 6) << 3);
            acc = fmaf(at[pix][t], bf2f(Ab[a]), acc);
            F += 128u;
        }
    }
    for (int t = A1; t < A2; ++t) {
        unsigned OFF_ = (F >= B1) ? OFFv[1] : OFFv[0];
        unsigned p = F & 4095u;
        unsigned a = OFF_ + p + ((p >> 6) << 3);
        acc = fmaf(at[pix][t], bf2f(Ab[a]), acc);
        F += 128u;
    }
    {
        const unsigned OFF_ = OFFv[1];
        #pragma unroll 4
        for (int t = A2; t < C1; ++t) {
            unsigned p = F & 4095u;
            unsigned a = OFF_ + p + ((p >> 6) << 3);
            acc = fmaf(at[pix][t], bf2f(Ab[a]), acc);
            F += 128u;
        }
    }
    for (int t = C1; t < C2; ++t) {
        unsigned OFF_ = (F >= B2) ? OFFv[2] : OFFv[1];
        unsigned p = F & 4095u;
        unsigned a = OFF_ + p + ((p >> 6) << 3);
        acc = fmaf(at[pix][t], bf2f(Ab[a]), acc);
        F += 128u;
    }
    {
        const unsigned OFF_ = OFFv[2];
        for (int t = C2; t < 49; ++t) {
            unsigned p = F & 4095u;
            unsigned a = OFF_ + p + ((p >> 6) << 3);
            acc = fmaf(at[pix][t], bf2f(Ab[a]), acc);
            F += 128u;
        }
    }

    // packed store
    const int kb = cc >> 5, k32 = cc & 31;
    const int quad = k32 >> 3, j = k32 & 7;
    const int pt16 = s >> 4, n = s & 15;
    y_p[((b * 4 + kb) * 256 + pt16) * 512 + (quad * 16 + n) * 8 + j] = f2bf(acc);
}

// ---------------------------------------------------------------------------
// maskconv_mfma: out[b,o,p] = x[b,o,p] + sum_cc wm[o,cc] y[p,cc].
// wm split hi/lo; all operands packed-fragment. 64x64 tile, K=128.
// ---------------------------------------------------------------------------
__global__ __launch_bounds__(256) void maskconv_mfma_kernel(
    const float* __restrict__ x,
    const unsigned short* __restrict__ wmp_hi,
    const unsigned short* __restrict__ wmp_lo,
    const unsigned short* __restrict__ y_p,
    float* __restrict__ out)
{
    const int tid = threadIdx.x;
    const int w   = tid >> 6;
    const int ln  = tid & 63;
    const int lm  = ln & 15;
    const int quad = ln >> 4;
    const int bx = blockIdx.x;   // px 64-tile
    const int ot = blockIdx.y;   // 0..3
    const int b  = blockIdx.z;
    const int ot16 = ot * 4 + w;
    const int lnofs = ln * 8;

    floatx4 acc0 = {0.f, 0.f, 0.f, 0.f};
    floatx4 acc1 = {0.f, 0.f, 0.f, 0.f};
    floatx4 acc2 = {0.f, 0.f, 0.f, 0.f};
    floatx4 acc3 = {0.f, 0.f, 0.f, 0.f};

    #pragma unroll
    for (int kb = 0; kb < 4; ++kb) {
        const int aoff = (ot16 * 4 + kb) * 512 + lnofs;
        const int boff = ((b * 4 + kb) * 256 + bx * 4) * 512 + lnofs;
        short8 ah = *reinterpret_cast<const short8*>(wmp_hi + aoff);
        short8 al = *reinterpret_cast<const short8*>(wmp_lo + aoff);
        short8 b0 = *reinterpret_cast<const short8*>(y_p + boff);
        short8 b1 = *reinterpret_cast<const short8*>(y_p + boff + 512);
        short8 b2 = *reinterpret_cast<const short8*>(y_p + boff + 1024);
        short8 b3 = *reinterpret_cast<const short8*>(y_p + boff + 1536);
        acc0 = __builtin_amdgcn_mfma_f32_16x16x32_bf16(ah, b0, acc0, 0, 0, 0);
        acc1 = __builtin_amdgcn_mfma_f32_16x16x32_bf16(ah, b1, acc1, 0, 0, 0);
        acc2 = __builtin_amdgcn_mfma_f32_16x16x32_bf16(ah, b2, acc2, 0, 0, 0);
        acc3 = __builtin_amdgcn_mfma_f32_16x16x32_bf16(ah, b3, acc3, 0, 0, 0);
        acc0 = __builtin_amdgcn_mfma_f32_16x16x32_bf16(al, b0, acc0, 0, 0, 0);
        acc1 = __builtin_amdgcn_mfma_f32_16x16x32_bf16(al, b1, acc1, 0, 0, 0);
        acc2 = __builtin_amdgcn_mfma_f32_16x16x32_bf16(al, b2, acc2, 0, 0, 0);
        acc3 = __builtin_amdgcn_mfma_f32_16x16x32_bf16(al, b3, acc3, 0, 0, 0);
    }

    floatx4 accs[4] = {acc0, acc1, acc2, acc3};
    const int o0 = ot16 * 16;
    #pragma unroll
    for (int ct = 0; ct < 4; ++ct) {
        const int p = bx * 64 + ct * 16 + lm;
        #pragma unroll
        for (int reg = 0; reg < 4; ++reg) {
            const int o = o0 + quad * 4 + reg;
            const int ofs = (b * 256 + o) * 4096 + p;
            out[ofs] = accs[ct][reg] + x[ofs];
        }
    }
}

extern "C" void kernel_launch(void* const* d_in, const int* in_sizes, int n_in,
                              void* d_out, int out_size, void* d_ws, size_t ws_size,
                              hipStream_t stream) {
    const float* x       = (const float*)d_in[0];
    const float* w_phi   = (const float*)d_in[1];
    const float* w_theta = (const float*)d_in[2];
    const float* w_g     = (const float*)d_in[3];
    const float* w_mask  = (const float*)d_in[4];

    float* out_f = (float*)d_out;

    unsigned short* ws_u  = (unsigned short*)d_ws;
    unsigned short* A_phi = ws_u;                      // 2,580,480 ush
    unsigned short* A_g   = ws_u + 2580480;            // 2,580,480 ush
    unsigned short* y_p   = ws_u + 5160960;            // 2,097,152 ush (packed)
    unsigned short* th_u  = ws_u + 7258112;            // 2,097,152 ush
    float*          sc_f  = (float*)(ws_u + 9355264);  // 1,048,576 fp32
    unsigned short* xph   = ws_u + 11452416;           // 4,194,304 ush
    unsigned short* xpl   = ws_u + 15646720;           // 4,194,304 ush
    unsigned short* w3ph  = ws_u + 19841024;           // 98,304 ush
    unsigned short* w3pl  = ws_u + 19939328;           // 98,304 ush
    unsigned short* wmph  = ws_u + 20037632;           // 32,768 ush
    unsigned short* wmpl  = ws_u + 20070400;           // 32,768 ush

    // 1: prep (packed operand build + zero planes)
    hipLaunchKernelGGL(prep_kernel, dim3(1152), dim3(256), 0, stream,
                       x, w_phi, w_theta, w_g, w_mask,
                       xph, xpl, w3ph, w3pl, wmph, wmpl, (uint4*)A_phi);
    // 2: conv3 via packed split-bf16 MFMA
    hipLaunchKernelGGL(conv3_mfma_kernel, dim3(64, 6, 4), dim3(256), 0, stream,
                       xph, xpl, w3ph, w3pl, A_phi, th_u, A_g);
    // 3: scores
    hipLaunchKernelGGL(scores_kernel, dim3(1024, 4), dim3(256), 0, stream,
                       A_phi, th_u, sc_f);
    // 4: softmax over h
    hipLaunchKernelGGL(softmax_kernel, dim3(256), dim3(256), 0, stream, sc_f);
    // 5: aggregate -> y packed
    hipLaunchKernelGGL(aggregate_kernel, dim3(2048, 4), dim3(256), 0, stream,
                       sc_f, A_g, y_p);
    // 6: maskconv via packed split-w MFMA + residual -> out
    hipLaunchKernelGGL(maskconv_mfma_kernel, dim3(64, 4, 4), dim3(256), 0, stream,
                       x, wmph, wmpl, y_p, out_f);
}

// Round 12
// 176.823 us; speedup vs baseline: 1.6765x; 1.0287x over previous
//
#include <hip/hip_runtime.h>

// Problem: b=4, c=256, ci=128, h=w=64 (HW=4096), field=7, kk=49. fp32 I/O.
//
// 6-dispatch pipeline; MFMA GEMMs (split-bf16 hi+lo) with operands PACKED in
// MFMA-fragment order (fragment = 512 ushorts; lane ln reads 16 B at
// frag_base + ln*16). A-frag elem[ln*8+j] = W[row=ln&15][k=(ln>>4)*8+j];
// B-frag elem[ln*8+j] = M[k=(ln>>4)*8+j][col=ln&15]; C/D col=lane&15,
// row=quad*4+reg (all r10/r11-verified).
//  1. prep: x -> xp_hi/lo packed; w3 -> w3p_hi/lo; wm -> wmp_hi/lo; zero planes.
//  2. conv3_mfma: one region (phi/theta/g) per block, 2 A-tiles/wave
//     (24 MFMAs : 12 loads per kb). phi/g -> padded planes, theta -> [p][cc].
//  3. scores: segmented flat-decode gather (verified r6-11).
//  4. softmax_stats: per (b,j,t): m and inv=1/sum only (no normalize pass).
//  5. aggregate: attn = exp(sc-m)*inv inline (bit-identical to r11), then
//     segmented gather; y stored packed.
//  6. maskconv_mfma: 2 o-tiles/wave, (wm_hi+wm_lo).y + x -> out fp32.
//
// Padded planes: [b][c0][70][72] bf16, data (py,px) at (py+3,px+4), zero
// borders; patch addr for F -> (ch=F>>12, p=F&4095):
//   a = OFF(ch) + p + 8*(p>>6), OFF(ch) = c0*5040 + kh*72 + kw + 1.
// Per-pixel F-range < 2*4096 -> <=3 ch values -> 3 pure + 2 mixed segments.
//
// ws layout (ushort units):
//   A_phi  @ 0          (2,580,480)
//   A_g    @ 2,580,480  (2,580,480)   (zeroed contiguously with A_phi)
//   y_p    @ 5,160,960  (2,097,152)   packed
//   theta  @ 7,258,112  (2,097,152)
//   scores @ 9,355,264  (2,097,152 ush = 1,048,576 fp32)
//   xp_hi  @ 11,452,416 (4,194,304)
//   xp_lo  @ 15,646,720 (4,194,304)
//   w3p_hi @ 19,841,024 (98,304)
//   w3p_lo @ 19,939,328 (98,304)
//   wmp_hi @ 20,037,632 (32,768)
//   wmp_lo @ 20,070,400 (32,768)
//   m_arr  @ 20,103,168 (25,088 ush = 12,544 fp32)
//   inv    @ 20,128,256 (25,088 ush = 12,544 fp32)   => ~40.3 MB total

#define PLANE    5040
#define A_BATCH  645120

typedef __attribute__((ext_vector_type(8))) short short8;
typedef __attribute__((ext_vector_type(4))) float floatx4;

__device__ __forceinline__ float bf2f(unsigned short u) {
    union { unsigned int i; float f; } v; v.i = ((unsigned int)u) << 16; return v.f;
}
__device__ __forceinline__ unsigned short f2bf(float f) {
    union { float f; unsigned int i; } v; v.f = f;
    unsigned int r = v.i + 0x7FFFu + ((v.i >> 16) & 1u);
    return (unsigned short)(r >> 16);
}

// ---------------------------------------------------------------------------
// prep: blocks [0,1024): x fp32 [b][k][p] -> packed hi/lo fragments.
// blocks [1024,1152): w3p/wmp hi/lo packed casts + zero plane regions.
// ---------------------------------------------------------------------------
__global__ __launch_bounds__(256) void prep_kernel(
    const float* __restrict__ x,
    const float* __restrict__ w_phi,
    const float* __restrict__ w_theta,
    const float* __restrict__ w_g,
    const float* __restrict__ w_mask,
    unsigned short* __restrict__ xp_hi,
    unsigned short* __restrict__ xp_lo,
    unsigned short* __restrict__ w3p_hi,
    unsigned short* __restrict__ w3p_lo,
    unsigned short* __restrict__ wmp_hi,
    unsigned short* __restrict__ wmp_lo,
    uint4* __restrict__ zero_region)
{
    const int tid = threadIdx.x;
    const int bx = blockIdx.x;

    if (bx < 1024) {
        const int b  = bx >> 8;          // batch
        const int kt = (bx >> 6) & 3;    // k 64-tile
        const int pt = bx & 63;          // p 64-tile
        __shared__ float tile[64][65];   // [k][p]
        #pragma unroll
        for (int i = 0; i < 16; ++i) {
            int lin = tid + i * 256;
            int kk = lin >> 6, pp = lin & 63;
            tile[kk][pp] = x[(b * 256 + kt * 64 + kk) * 4096 + pt * 64 + pp];
        }
        __syncthreads();
        #pragma unroll
        for (int i = 0; i < 16; ++i) {
            int lin = tid + i * 256;
            int frag = lin >> 9;          // 0..7
            int idx  = lin & 511;
            int kbL  = frag >> 2;         // 0..1
            int ptL  = frag & 3;          // 0..3
            int j    = idx & 7;
            int n    = (idx >> 3) & 15;
            int quad = idx >> 7;
            float f = tile[kbL * 32 + quad * 8 + j][ptL * 16 + n];
            unsigned short h = f2bf(f);
            int addr = ((b * 8 + kt * 2 + kbL) * 256 + pt * 4 + ptL) * 512 + idx;
            xp_hi[addr] = h;
            xp_lo[addr] = f2bf(f - bf2f(h));
        }
    } else {
        const int wid = (bx - 1024) * 256 + tid;   // 0..32767
        for (int e = wid; e < 98304; e += 32768) {
            int frag = e >> 9;            // 0..191
            int idx  = e & 511;
            int nt16 = frag >> 3, kb = frag & 7;
            int j = idx & 7, m = (idx >> 3) & 15, quad = idx >> 7;
            int n = nt16 * 16 + m;
            int k = kb * 32 + quad * 8 + j;
            float v = (n < 128) ? w_phi[n * 256 + k]
                    : (n < 256) ? w_theta[(n - 128) * 256 + k]
                                : w_g[(n - 256) * 256 + k];
            unsigned short h = f2bf(v);
            w3p_hi[e] = h;
            w3p_lo[e] = f2bf(v - bf2f(h));
        }
        {
            int e = wid;                  // exactly covers wmp
            int frag = e >> 9;            // 0..63
            int idx  = e & 511;
            int ot16 = frag >> 2, kb = frag & 3;
            int j = idx & 7, m = (idx >> 3) & 15, quad = idx >> 7;
            float v = w_mask[(ot16 * 16 + m) * 128 + kb * 32 + quad * 8 + j];
            unsigned short h = f2bf(v);
            wmp_hi[e] = h;
            wmp_lo[e] = f2bf(v - bf2f(h));
        }
        const uint4 z = make_uint4(0u, 0u, 0u, 0u);
        for (int i = wid; i < 645120; i += 32768) zero_region[i] = z;
    }
}

// ---------------------------------------------------------------------------
// conv3_mfma: one REGION per block (nt: 0=phi 1=theta 2=g, 128 rows).
// Wave w handles region rows [w*16,+16) (tile a) and [64+w*16,+16) (tile b)
// over 64 px. 24 MFMAs : 12 fragment loads per kb. Split hi/lo.
// ---------------------------------------------------------------------------
__global__ __launch_bounds__(256) void conv3_mfma_kernel(
    const unsigned short* __restrict__ xp_hi,
    const unsigned short* __restrict__ xp_lo,
    const unsigned short* __restrict__ w3p_hi,
    const unsigned short* __restrict__ w3p_lo,
    unsigned short* __restrict__ A_phi,
    unsigned short* __restrict__ theta_bf,
    unsigned short* __restrict__ A_g)
{
    const int tid = threadIdx.x;
    const int w   = tid >> 6;
    const int ln  = tid & 63;
    const int lm  = ln & 15;
    const int quad = ln >> 4;
    const int bx = blockIdx.x;   // px 64-tile; py = bx
    const int nt = blockIdx.y;   // region 0..2
    const int b  = blockIdx.z;
    const int nt16a = nt * 8 + w;
    const int nt16b = nt * 8 + 4 + w;
    const int lnofs = ln * 8;

    floatx4 accA[4] = {{0.f,0.f,0.f,0.f},{0.f,0.f,0.f,0.f},
                       {0.f,0.f,0.f,0.f},{0.f,0.f,0.f,0.f}};
    floatx4 accB[4] = {{0.f,0.f,0.f,0.f},{0.f,0.f,0.f,0.f},
                       {0.f,0.f,0.f,0.f},{0.f,0.f,0.f,0.f}};

    #pragma unroll
    for (int kb = 0; kb < 8; ++kb) {
        const int aoffA = (nt16a * 8 + kb) * 512 + lnofs;
        const int aoffB = (nt16b * 8 + kb) * 512 + lnofs;
        const int boff  = ((b * 8 + kb) * 256 + bx * 4) * 512 + lnofs;
        short8 ahA = *reinterpret_cast<const short8*>(w3p_hi + aoffA);
        short8 alA = *reinterpret_cast<const short8*>(w3p_lo + aoffA);
        short8 ahB = *reinterpret_cast<const short8*>(w3p_hi + aoffB);
        short8 alB = *reinterpret_cast<const short8*>(w3p_lo + aoffB);
        short8 bh[4], bl[4];
        #pragma unroll
        for (int ct = 0; ct < 4; ++ct) {
            bh[ct] = *reinterpret_cast<const short8*>(xp_hi + boff + ct * 512);
            bl[ct] = *reinterpret_cast<const short8*>(xp_lo + boff + ct * 512);
        }
        #pragma unroll
        for (int ct = 0; ct < 4; ++ct) {
            accA[ct] = __builtin_amdgcn_mfma_f32_16x16x32_bf16(ahA, bh[ct], accA[ct], 0, 0, 0);
            accA[ct] = __builtin_amdgcn_mfma_f32_16x16x32_bf16(ahA, bl[ct], accA[ct], 0, 0, 0);
            accA[ct] = __builtin_amdgcn_mfma_f32_16x16x32_bf16(alA, bh[ct], accA[ct], 0, 0, 0);
            accB[ct] = __builtin_amdgcn_mfma_f32_16x16x32_bf16(ahB, bh[ct], accB[ct], 0, 0, 0);
            accB[ct] = __builtin_amdgcn_mfma_f32_16x16x32_bf16(ahB, bl[ct], accB[ct], 0, 0, 0);
            accB[ct] = __builtin_amdgcn_mfma_f32_16x16x32_bf16(alB, bh[ct], accB[ct], 0, 0, 0);
        }
    }

    const int py = bx;
    if (nt == 1) {
        // theta: cc = region row, store theta_bf[(b*4096+p)*128 + cc]
        #pragma unroll
        for (int ct = 0; ct < 4; ++ct) {
            const int p = bx * 64 + ct * 16 + lm;
            #pragma unroll
            for (int reg = 0; reg < 4; ++reg) {
                const int r = w * 16 + quad * 4 + reg;
                theta_bf[(b * 4096 + p) * 128 + r]      = f2bf(accA[ct][reg]);
                theta_bf[(b * 4096 + p) * 128 + r + 64] = f2bf(accB[ct][reg]);
            }
        }
    } else {
        unsigned short* __restrict__ A = (nt == 0) ? A_phi : A_g;
        #pragma unroll
        for (int ct = 0; ct < 4; ++ct) {
            const int pxx = ct * 16 + lm;
            #pragma unroll
            for (int reg = 0; reg < 4; ++reg) {
                const int r = w * 16 + quad * 4 + reg;
                A[b * A_BATCH + r * PLANE + (py + 3) * 72 + pxx + 4] =
                    f2bf(accA[ct][reg]);
                A[b * A_BATCH + (r + 64) * PLANE + (py + 3) * 72 + pxx + 4] =
                    f2bf(accB[ct][reg]);
            }
        }
    }
}

// ---------------------------------------------------------------------------
// scores: wave per pixel s, lane = t. 3 pure + 2 mixed cc-segments over
// padded phi planes. scores fp32 slots [b][s][64] (first 49 used).
// ---------------------------------------------------------------------------
__global__ __launch_bounds__(256) void scores_kernel(
    const unsigned short* __restrict__ Apad,
    const unsigned short* __restrict__ theta_bf,
    float* __restrict__ scores)
{
    const int w  = threadIdx.x >> 6;
    const int ln = threadIdx.x & 63;
    const int s  = blockIdx.x * 4 + w;
    const int b  = blockIdx.y;

    __shared__ float th[4][128];
    {
        const unsigned short* tb = theta_bf + (b * 4096 + s) * 128;
        th[w][ln]      = bf2f(tb[ln]);
        th[w][ln + 64] = bf2f(tb[ln + 64]);
    }
    __syncthreads();

    const unsigned short* __restrict__ Ab = Apad + b * A_BATCH;

    const int base  = s * 6272;
    const int ch_lo = base >> 12;
    const unsigned B1 = (unsigned)(ch_lo + 1) << 12;
    const unsigned B2 = (unsigned)(ch_lo + 2) << 12;
    const int d1 = (int)B1 - base;
    const int d2 = d1 + 4096;

    int A1 = d1 / 49;
    int A2 = (d1 + 48) / 49;
    int C1 = d2 / 49;        if (C1 > 128) C1 = 128;
    int C2 = (d2 + 48) / 49; if (C2 > 128) C2 = 128;

    unsigned OFFv[3];
    #pragma unroll
    for (int i = 0; i < 3; ++i) {
        int ch = ch_lo + i;
        int c0 = ch / 49; if (c0 > 127) c0 = 127;
        int rr = ch - c0 * 49;
        int kh = rr / 7;
        int kw = rr - kh * 7;
        OFFv[i] = (unsigned)(c0 * PLANE + kh * 72 + kw + 1);
    }

    unsigned F = (unsigned)(base + ln);
    float acc = 0.f;

    {
        const unsigned OFF_ = OFFv[0];
        #pragma unroll 4
        for (int cc = 0; cc < A1; ++cc) {
            unsigned p = F & 4095u;
            unsigned a = OFF_ + p + ((p >> 6) << 3);
            acc = fmaf(th[w][cc], bf2f(Ab[a]), acc);
            F += 49u;
        }
    }
    for (int cc = A1; cc < A2; ++cc) {
        unsigned OFF_ = (F >= B1) ? OFFv[1] : OFFv[0];
        unsigned p = F & 4095u;
        unsigned a = OFF_ + p + ((p >> 6) << 3);
        acc = fmaf(th[w][cc], bf2f(Ab[a]), acc);
        F += 49u;
    }
    {
        const unsigned OFF_ = OFFv[1];
        #pragma unroll 4
        for (int cc = A2; cc < C1; ++cc) {
            unsigned p = F & 4095u;
            unsigned a = OFF_ + p + ((p >> 6) << 3);
            acc = fmaf(th[w][cc], bf2f(Ab[a]), acc);
            F += 49u;
        }
    }
    for (int cc = C1; cc < C2; ++cc) {
        unsigned OFF_ = (F >= B2) ? OFFv[2] : OFFv[1];
        unsigned p = F & 4095u;
        unsigned a = OFF_ + p + ((p >> 6) << 3);
        acc = fmaf(th[w][cc], bf2f(Ab[a]), acc);
        F += 49u;
    }
    {
        const unsigned OFF_ = OFFv[2];
        #pragma unroll 4
        for (int cc = C2; cc < 128; ++cc) {
            unsigned p = F & 4095u;
            unsigned a = OFF_ + p + ((p >> 6) << 3);
            acc = fmaf(th[w][cc], bf2f(Ab[a]), acc);
            F += 49u;
        }
    }

    if (ln < 49) scores[(b * 4096 + s) * 64 + ln] = acc;
}

// ---------------------------------------------------------------------------
// softmax_stats: per (b,j,t) compute m = max_i sc, inv = 1/sum_i exp(sc-m).
// Block per (b,j); LDS tile 64(i) x 49(t). No normalize write-back.
// ---------------------------------------------------------------------------
__global__ __launch_bounds__(256) void softmax_stats_kernel(
    const float* __restrict__ scores,
    float* __restrict__ m_arr,
    float* __restrict__ inv_arr)
{
    const int b = blockIdx.x >> 6;
    const int j = blockIdx.x & 63;
    const int tid = threadIdx.x;
    const int wv = tid >> 6;
    const int ln = tid & 63;

    __shared__ float tile[64][52];

    #pragma unroll
    for (int it = 0; it < 16; ++it) {
        int i = it * 4 + wv;
        if (ln < 49) tile[i][ln] = scores[(b * 4096 + i * 64 + j) * 64 + ln];
    }
    __syncthreads();

    if (tid < 49) {
        float m = -3.4e38f;
        #pragma unroll 8
        for (int i = 0; i < 64; ++i) m = fmaxf(m, tile[i][tid]);
        float sum = 0.f;
        #pragma unroll 8
        for (int i = 0; i < 64; ++i) sum += __expf(tile[i][tid] - m);
        m_arr[(b * 64 + j) * 49 + tid]   = m;
        inv_arr[(b * 64 + j) * 49 + tid] = 1.f / sum;
    }
}

// ---------------------------------------------------------------------------
// aggregate: 2 pixels/block, lane = cc (128). attn computed inline:
// attn[t] = exp(sc[t]-m[j][t]) * inv[j][t]  (bit-identical to r11 path).
// Segment trick over t; y stored packed.
// ---------------------------------------------------------------------------
__global__ __launch_bounds__(256) void aggregate_kernel(
    const float* __restrict__ scores,
    const float* __restrict__ m_arr,
    const float* __restrict__ inv_arr,
    const unsigned short* __restrict__ Apad,
    unsigned short* __restrict__ y_p)
{
    const int pix = threadIdx.x >> 7;
    const int cc  = threadIdx.x & 127;
    const int s   = blockIdx.x * 2 + pix;
    const int b   = blockIdx.y;

    __shared__ float at[2][52];
    if (cc < 49) {
        const int j = s & 63;
        float sc = scores[(b * 4096 + s) * 64 + cc];
        float m  = m_arr[(b * 64 + j) * 49 + cc];
        float iv = inv_arr[(b * 64 + j) * 49 + cc];
        at[pix][cc] = __expf(sc - m) * iv;
    }
    __syncthreads();

    const unsigned short* __restrict__ Ab = Apad + b * A_BATCH;

    const int base  = s * 6272;
    const int ch_lo = base >> 12;
    const unsigned B1 = (unsigned)(ch_lo + 1) << 12;
    const unsigned B2 = (unsigned)(ch_lo + 2) << 12;
    const int d1 = (int)B1 - base;
    const int d2 = d1 + 4096;

    int A1 = d1 >> 7;
    int A2 = (d1 + 127) >> 7;
    int C1 = d2 >> 7;          if (C1 > 49) C1 = 49;
    int C2 = (d2 + 127) >> 7;  if (C2 > 49) C2 = 49;
    if (A1 > 49) A1 = 49;
    if (A2 > 49) A2 = 49;

    unsigned OFFv[3];
    #pragma unroll
    for (int i = 0; i < 3; ++i) {
        int ch = ch_lo + i;
        int c0 = ch / 49; if (c0 > 127) c0 = 127;
        int rr = ch - c0 * 49;
        int kh = rr / 7;
        int kw = rr - kh * 7;
        OFFv[i] = (unsigned)(c0 * PLANE + kh * 72 + kw + 1);
    }

    unsigned F = (unsigned)(base + cc);
    float acc = 0.f;

    {
        const unsigned OFF_ = OFFv[0];
        #pragma unroll 4
        for (int t = 0; t < A1; ++t) {
            unsigned p = F & 4095u;
            unsigned a = OFF_ + p + ((p >> 6) << 3);
            acc = fmaf(at[pix][t], bf2f(Ab[a]), acc);
            F += 128u;
        }
    }
    for (int t = A1; t < A2; ++t) {
        unsigned OFF_ = (F >= B1) ? OFFv[1] : OFFv[0];
        unsigned p = F & 4095u;
        unsigned a = OFF_ + p + ((p >> 6) << 3);
        acc = fmaf(at[pix][t], bf2f(Ab[a]), acc);
        F += 128u;
    }
    {
        const unsigned OFF_ = OFFv[1];
        #pragma unroll 4
        for (int t = A2; t < C1; ++t) {
            unsigned p = F & 4095u;
            unsigned a = OFF_ + p + ((p >> 6) << 3);
            acc = fmaf(at[pix][t], bf2f(Ab[a]), acc);
            F += 128u;
        }
    }
    for (int t = C1; t < C2; ++t) {
        unsigned OFF_ = (F >= B2) ? OFFv[2] : OFFv[1];
        unsigned p = F & 4095u;
        unsigned a = OFF_ + p + ((p >> 6) << 3);
        acc = fmaf(at[pix][t], bf2f(Ab[a]), acc);
        F += 128u;
    }
    {
        const unsigned OFF_ = OFFv[2];
        for (int t = C2; t < 49; ++t) {
            unsigned p = F & 4095u;
            unsigned a = OFF_ + p + ((p >> 6) << 3);
            acc = fmaf(at[pix][t], bf2f(Ab[a]), acc);
            F += 128u;
        }
    }

    // packed store
    const int kb = cc >> 5, k32 = cc & 31;
    const int quad = k32 >> 3, j = k32 & 7;
    const int pt16 = s >> 4, n = s & 15;
    y_p[((b * 4 + kb) * 256 + pt16) * 512 + (quad * 16 + n) * 8 + j] = f2bf(acc);
}

// ---------------------------------------------------------------------------
// maskconv_mfma: out[b,o,p] = x[b,o,p] + sum_cc wm[o,cc] y[p,cc].
// 2 o-tiles per wave (ot covers 128 rows), wm split hi/lo, K=128.
// ---------------------------------------------------------------------------
__global__ __launch_bounds__(256) void maskconv_mfma_kernel(
    const float* __restrict__ x,
    const unsigned short* __restrict__ wmp_hi,
    const unsigned short* __restrict__ wmp_lo,
    const unsigned short* __restrict__ y_p,
    float* __restrict__ out)
{
    const int tid = threadIdx.x;
    const int w   = tid >> 6;
    const int ln  = tid & 63;
    const int lm  = ln & 15;
    const int quad = ln >> 4;
    const int bx = blockIdx.x;   // px 64-tile
    const int ot = blockIdx.y;   // 0..1 (128 o-rows each)
    const int b  = blockIdx.z;
    const int ot16a = ot * 8 + w;
    const int ot16b = ot * 8 + 4 + w;
    const int lnofs = ln * 8;

    floatx4 accA[4] = {{0.f,0.f,0.f,0.f},{0.f,0.f,0.f,0.f},
                       {0.f,0.f,0.f,0.f},{0.f,0.f,0.f,0.f}};
    floatx4 accB[4] = {{0.f,0.f,0.f,0.f},{0.f,0.f,0.f,0.f},
                       {0.f,0.f,0.f,0.f},{0.f,0.f,0.f,0.f}};

    #pragma unroll
    for (int kb = 0; kb < 4; ++kb) {
        const int aoffA = (ot16a * 4 + kb) * 512 + lnofs;
        const int aoffB = (ot16b * 4 + kb) * 512 + lnofs;
        const int boff  = ((b * 4 + kb) * 256 + bx * 4) * 512 + lnofs;
        short8 ahA = *reinterpret_cast<const short8*>(wmp_hi + aoffA);
        short8 alA = *reinterpret_cast<const short8*>(wmp_lo + aoffA);
        short8 ahB = *reinterpret_cast<const short8*>(wmp_hi + aoffB);
        short8 alB = *reinterpret_cast<const short8*>(wmp_lo + aoffB);
        short8 bf[4];
        #pragma unroll
        for (int ct = 0; ct < 4; ++ct)
            bf[ct] = *reinterpret_cast<const short8*>(y_p + boff + ct * 512);
        #pragma unroll
        for (int ct = 0; ct < 4; ++ct) {
            accA[ct] = __builtin_amdgcn_mfma_f32_16x16x32_bf16(ahA, bf[ct], accA[ct], 0, 0, 0);
            accA[ct] = __builtin_amdgcn_mfma_f32_16x16x32_bf16(alA, bf[ct], accA[ct], 0, 0, 0);
            accB[ct] = __builtin_amdgcn_mfma_f32_16x16x32_bf16(ahB, bf[ct], accB[ct], 0, 0, 0);
            accB[ct] = __builtin_amdgcn_mfma_f32_16x16x32_bf16(alB, bf[ct], accB[ct], 0, 0, 0);
        }
    }

    #pragma unroll
    for (int ct = 0; ct < 4; ++ct) {
        const int p = bx * 64 + ct * 16 + lm;
        #pragma unroll
        for (int reg = 0; reg < 4; ++reg) {
            const int oA = ot * 128 + w * 16 + quad * 4 + reg;
            const int ofsA = (b * 256 + oA) * 4096 + p;
            out[ofsA] = accA[ct][reg] + x[ofsA];
            const int ofsB = ofsA + 64 * 4096;
            out[ofsB] = accB[ct][reg] + x[ofsB];
        }
    }
}

extern "C" void kernel_launch(void* const* d_in, const int* in_sizes, int n_in,
                              void* d_out, int out_size, void* d_ws, size_t ws_size,
                              hipStream_t stream) {
    const float* x       = (const float*)d_in[0];
    const float* w_phi   = (const float*)d_in[1];
    const float* w_theta = (const float*)d_in[2];
    const float* w_g     = (const float*)d_in[3];
    const float* w_mask  = (const float*)d_in[4];

    float* out_f = (float*)d_out;

    unsigned short* ws_u  = (unsigned short*)d_ws;
    unsigned short* A_phi = ws_u;                      // 2,580,480 ush
    unsigned short* A_g   = ws_u + 2580480;            // 2,580,480 ush
    unsigned short* y_p   = ws_u + 5160960;            // 2,097,152 ush (packed)
    unsigned short* th_u  = ws_u + 7258112;            // 2,097,152 ush
    float*          sc_f  = (float*)(ws_u + 9355264);  // 1,048,576 fp32
    unsigned short* xph   = ws_u + 11452416;           // 4,194,304 ush
    unsigned short* xpl   = ws_u + 15646720;           // 4,194,304 ush
    unsigned short* w3ph  = ws_u + 19841024;           // 98,304 ush
    unsigned short* w3pl  = ws_u + 19939328;           // 98,304 ush
    unsigned short* wmph  = ws_u + 20037632;           // 32,768 ush
    unsigned short* wmpl  = ws_u + 20070400;           // 32,768 ush
    float*          m_f   = (float*)(ws_u + 20103168); // 12,544 fp32
    float*          inv_f = (float*)(ws_u + 20128256); // 12,544 fp32

    // 1: prep (packed operand build + zero planes)
    hipLaunchKernelGGL(prep_kernel, dim3(1152), dim3(256), 0, stream,
                       x, w_phi, w_theta, w_g, w_mask,
                       xph, xpl, w3ph, w3pl, wmph, wmpl, (uint4*)A_phi);
    // 2: conv3 via packed split-bf16 MFMA (one region per block)
    hipLaunchKernelGGL(conv3_mfma_kernel, dim3(64, 3, 4), dim3(256), 0, stream,
                       xph, xpl, w3ph, w3pl, A_phi, th_u, A_g);
    // 3: scores
    hipLaunchKernelGGL(scores_kernel, dim3(1024, 4), dim3(256), 0, stream,
                       A_phi, th_u, sc_f);
    // 4: softmax stats (m, inv) only
    hipLaunchKernelGGL(softmax_stats_kernel, dim3(256), dim3(256), 0, stream,
                       sc_f, m_f, inv_f);
    // 5: aggregate (attn inline) -> y packed
    hipLaunchKernelGGL(aggregate_kernel, dim3(2048, 4), dim3(256), 0, stream,
                       sc_f, m_f, inv_f, A_g, y_p);
    // 6: maskconv via packed split-w MFMA + residual -> out
    hipLaunchKernelGGL(maskconv_mfma_kernel, dim3(64, 2, 4), dim3(256), 0, stream,
                       x, wmph, wmpl, y_p, out_f);
}